// Round 1
// baseline (7050.328 us; speedup 1.0000x reference)
//
#include <hip/hip_runtime.h>
#include <hip/hip_bf16.h>

#define VSZ   32000
#define EMBD  512
#define HIDD  1024
#define BB    64
#define TSEQ  512
#define INSZ  2560
#define G4    4096

__device__ __forceinline__ float sigmoid_f(float x){ return 1.0f/(1.0f+__expf(-x)); }

__device__ __forceinline__ float wave_sum(float x){
  #pragma unroll
  for (int off=32; off>0; off>>=1) x += __shfl_xor(x, off);
  return x;
}
__device__ __forceinline__ float wave_max(float x){
  #pragma unroll
  for (int off=32; off>0; off>>=1) x = fmaxf(x, __shfl_xor(x, off));
  return x;
}

// ---------------- K1: embedding gather ----------------
__global__ __launch_bounds__(128) void k_embed(const int* __restrict__ y,
                                               const float* __restrict__ tab,
                                               float* __restrict__ emb){
  int b = blockIdx.x;
  int row = y[b];
  const float4* src = (const float4*)(tab + (size_t)row*EMBD);
  float4* dst = (float4*)(emb + (size_t)b*EMBD);
  dst[threadIdx.x] = src[threadIdx.x];   // 128 float4 = 512 floats
}

// ---------------- K2: q projections (q_e = h@Wq_e^T, q_b = h@Wq_b^T) ----------------
__global__ __launch_bounds__(256) void k_qproj(const float* __restrict__ h,
                                               const float* __restrict__ Wqe,
                                               const float* __restrict__ Wqb,
                                               float* __restrict__ qe,
                                               float* __restrict__ qb){
  int wid  = blockIdx.x*4 + (threadIdx.x>>6);  // 131072 waves total
  int lane = threadIdx.x & 63;
  int sel  = wid >> 16;
  int id   = wid & 0xFFFF;
  int b = id >> 10, a = id & 1023;
  const float4* W4 = (const float4*)((sel ? Wqb : Wqe) + (size_t)a*HIDD);
  const float4* h4 = (const float4*)(h + (size_t)b*HIDD);
  float acc = 0.f;
  #pragma unroll
  for (int i=0;i<4;i++){
    float4 wv = W4[i*64+lane]; float4 hv = h4[i*64+lane];
    acc += wv.x*hv.x + wv.y*hv.y + wv.z*hv.z + wv.w*hv.w;
  }
  acc = wave_sum(acc);
  if (lane==0) (sel ? qb : qe)[id] = acc;
}

// ---------------- K3: attention energies e[b,t] = v . tanh(q[b] + Wk @ keys[b,t]) ----------------
// grid (32 t-tiles, 64 b), block 256 (4 waves). 16 t's per block, LDS key tile.
__global__ __launch_bounds__(256) void k_energy(const float* __restrict__ keys,
                                                const float* __restrict__ Wk,
                                                const float* __restrict__ q,
                                                const float* __restrict__ v,
                                                const int* __restrict__ mask,
                                                float* __restrict__ e_out){
  __shared__ float key_s[16*1024];
  __shared__ float q_s[1024];
  __shared__ float v_s[1024];
  __shared__ float kbuf[16][17];
  __shared__ float ebuf[16][17];
  int b = blockIdx.y, t0 = blockIdx.x*16;
  int tid = threadIdx.x, lane = tid & 63, w = tid >> 6;

  const float4* kg = (const float4*)(keys + ((size_t)b*TSEQ + t0)*1024);
  float4* ks4 = (float4*)key_s;
  #pragma unroll
  for (int i=0;i<16;i++) ks4[i*256 + tid] = kg[i*256 + tid];
  ((float4*)q_s)[tid] = ((const float4*)(q + (size_t)b*1024))[tid];
  ((float4*)v_s)[tid] = ((const float4*)v)[tid];
  __syncthreads();

  int tphase = tid >> 4, aphase = tid & 15;
  float epart = 0.f;

  for (int it=0; it<64; ++it){
    int a0 = it*16 + w*4;
    float wf[4][16];
    #pragma unroll
    for (int aa=0;aa<4;aa++){
      const float* row = Wk + (size_t)(a0+aa)*1024;
      #pragma unroll
      for (int j=0;j<16;j++) wf[aa][j] = row[j*64+lane];   // coalesced, L2-resident
    }
    #pragma unroll 1
    for (int t=0;t<16;t++){
      float s0=0.f,s1=0.f,s2=0.f,s3=0.f;
      #pragma unroll
      for (int j=0;j<16;j++){
        float kv = key_s[t*1024 + j*64 + lane];            // conflict-free (2/bank)
        s0 += wf[0][j]*kv; s1 += wf[1][j]*kv; s2 += wf[2][j]*kv; s3 += wf[3][j]*kv;
      }
      #pragma unroll
      for (int off=32; off>0; off>>=1){
        s0 += __shfl_xor(s0, off); s1 += __shfl_xor(s1, off);
        s2 += __shfl_xor(s2, off); s3 += __shfl_xor(s3, off);
      }
      if (lane==0){
        kbuf[t][w*4+0]=s0; kbuf[t][w*4+1]=s1; kbuf[t][w*4+2]=s2; kbuf[t][w*4+3]=s3;
      }
    }
    __syncthreads();
    // distributed tanh: 256 threads cover the 16x16 kbuf
    int a = it*16 + aphase;
    epart += v_s[a]*tanhf(q_s[a] + kbuf[tphase][aphase]);
    __syncthreads();
  }
  ebuf[tphase][aphase] = epart;
  __syncthreads();
  if (tid < 16){
    float s = 0.f;
    #pragma unroll
    for (int j=0;j<16;j++) s += ebuf[tid][j];
    int t = t0 + tid;
    if (mask && mask[(size_t)b*TSEQ + t]==0) s = -3.4e38f;
    e_out[(size_t)b*TSEQ + t] = s;
  }
}

// ---------------- K4: softmax over T for both attentions, in place ----------------
__global__ __launch_bounds__(256) void k_softmax_t(float* __restrict__ e_enc,
                                                   float* __restrict__ e_bwd){
  float* e = (blockIdx.y==0 ? e_enc : e_bwd) + (size_t)blockIdx.x*TSEQ;
  __shared__ float red[8];
  int tid = threadIdx.x, lane = tid & 63, w = tid >> 6;
  float v0 = e[tid], v1 = e[tid+256];
  float m = wave_max(fmaxf(v0, v1));
  if (lane==0) red[w] = m;
  __syncthreads();
  m = fmaxf(fmaxf(red[0],red[1]), fmaxf(red[2],red[3]));
  float x0 = __expf(v0-m), x1 = __expf(v1-m);
  float s = wave_sum(x0+x1);
  if (lane==0) red[4+w] = s;
  __syncthreads();
  s = red[4]+red[5]+red[6]+red[7];
  float inv = 1.0f/s;
  e[tid] = x0*inv; e[tid+256] = x1*inv;
}

// ---------------- K5: context = attn @ keys (t-split partials) ----------------
__global__ __launch_bounds__(256) void k_ctx(const float* __restrict__ enc,
                                             const float* __restrict__ bwdst,
                                             const float* __restrict__ att_e,
                                             const float* __restrict__ att_b,
                                             float* __restrict__ ctxp){
  int b = blockIdx.x, sel = blockIdx.y, s = blockIdx.z;
  const float* keys = (sel ? bwdst : enc) + ((size_t)b*TSEQ + s*64)*1024;
  const float* att  = (sel ? att_b : att_e) + (size_t)b*TSEQ + s*64;
  int tid = threadIdx.x;
  float acc[4] = {0.f,0.f,0.f,0.f};
  for (int t=0;t<64;t++){
    float a = att[t];
    #pragma unroll
    for (int i=0;i<4;i++) acc[i] += a*keys[(size_t)t*1024 + i*256 + tid];
  }
  float* o = ctxp + (((size_t)sel*BB + b)*8 + s)*1024;
  #pragma unroll
  for (int i=0;i<4;i++) o[i*256+tid] = acc[i];
}

__global__ __launch_bounds__(256) void k_ctxred(const float* __restrict__ ctxp,
                                                float* __restrict__ ctx_e,
                                                float* __restrict__ ctx_b){
  int id = blockIdx.x*256 + threadIdx.x;        // 131072
  int sel = id >> 16; int rem = id & 65535; int b = rem >> 10; int d = rem & 1023;
  const float* p = ctxp + (((size_t)sel*BB + b)*8)*1024 + d;
  float s = 0.f;
  #pragma unroll
  for (int i=0;i<8;i++) s += p[i*1024];
  (sel ? ctx_b : ctx_e)[(size_t)b*1024 + d] = s;
}

// ---------------- K6: LSTM gates = x@W_ih^T + h@W_hh^T + b ----------------
__global__ __launch_bounds__(256) void k_gates(const float* __restrict__ emb,
                                               const float* __restrict__ ctxe,
                                               const float* __restrict__ ctxb,
                                               const float* __restrict__ h,
                                               const float* __restrict__ W_ih,
                                               const float* __restrict__ W_hh,
                                               const float* __restrict__ b_ih,
                                               const float* __restrict__ b_hh,
                                               float* __restrict__ gates){
  int wid  = blockIdx.x*4 + (threadIdx.x>>6);   // 262144 waves
  int lane = threadIdx.x & 63;
  int b = wid >> 12, gg = wid & 4095;
  const float4* Wi = (const float4*)(W_ih + (size_t)gg*INSZ);
  const float4* Wh = (const float4*)(W_hh + (size_t)gg*HIDD);
  const float4* e4  = (const float4*)(emb  + (size_t)b*EMBD);
  const float4* ce4 = (const float4*)(ctxe + (size_t)b*HIDD);
  const float4* cb4 = (const float4*)(ctxb + (size_t)b*HIDD);
  const float4* h4  = (const float4*)(h    + (size_t)b*HIDD);
  float acc = 0.f;
  #pragma unroll
  for (int cc=0; cc<10; cc++){
    float4 wv = Wi[cc*64+lane];
    float4 xv = (cc<2) ? e4[cc*64+lane] : (cc<6 ? ce4[(cc-2)*64+lane] : cb4[(cc-6)*64+lane]);
    acc += wv.x*xv.x + wv.y*xv.y + wv.z*xv.z + wv.w*xv.w;
  }
  #pragma unroll
  for (int cc=0; cc<4; cc++){
    float4 wv = Wh[cc*64+lane]; float4 hv = h4[cc*64+lane];
    acc += wv.x*hv.x + wv.y*hv.y + wv.z*hv.z + wv.w*hv.w;
  }
  acc = wave_sum(acc);
  if (lane==0) gates[(size_t)b*G4 + gg] = acc + b_ih[gg] + b_hh[gg];
}

// ---------------- K7: LSTM cell ----------------
__global__ __launch_bounds__(256) void k_lstm(const float* __restrict__ gates,
                                              const float* __restrict__ c_old,
                                              float* __restrict__ out){
  int id = blockIdx.x*256 + threadIdx.x;        // 65536
  int b = id >> 10, j = id & 1023;
  const float* g = gates + (size_t)b*G4;
  float ig = sigmoid_f(g[j]);
  float fg = sigmoid_f(g[1024+j]);
  float gg = tanhf(g[2048+j]);
  float og = sigmoid_f(g[3072+j]);
  float cn = fg*c_old[id] + ig*gg;
  float hn = og*tanhf(cn);
  out[(size_t)BB*VSZ + id] = hn;
  out[(size_t)BB*VSZ + (size_t)BB*HIDD + id] = cn;
}

// ---------------- K8: vocab logits = h_new @ Wp^T + bp ----------------
// h_new staged bf16 in LDS (128KB); each wave: 4 vocab rows x all 64 batches.
__global__ __launch_bounds__(256) void k_vocab(const float* __restrict__ hn_src,
                                               const float* __restrict__ Wp,
                                               const float* __restrict__ bp,
                                               float* __restrict__ out){
  __shared__ __hip_bfloat16 h_s[BB*HIDD];       // 128 KB
  int tid = threadIdx.x;
  for (int i=0;i<256;i++) h_s[i*256+tid] = __float2bfloat16(hn_src[i*256+tid]);
  __syncthreads();
  int w = tid>>6, lane = tid&63;
  int v0 = blockIdx.x*16 + w*4;
  float rf[4][16];
  #pragma unroll
  for (int aa=0;aa<4;aa++){
    const float* row = Wp + (size_t)(v0+aa)*HIDD;
    #pragma unroll
    for (int i=0;i<16;i++) rf[aa][i] = row[lane + i*64];
  }
  for (int b=0;b<BB;b++){
    float a0=0.f,a1=0.f,a2=0.f,a3=0.f;
    #pragma unroll
    for (int i=0;i<16;i++){
      float hv = __bfloat162float(h_s[b*HIDD + lane + i*64]);
      a0 += rf[0][i]*hv; a1 += rf[1][i]*hv; a2 += rf[2][i]*hv; a3 += rf[3][i]*hv;
    }
    #pragma unroll
    for (int off=32; off>0; off>>=1){
      a0 += __shfl_xor(a0,off); a1 += __shfl_xor(a1,off);
      a2 += __shfl_xor(a2,off); a3 += __shfl_xor(a3,off);
    }
    if (lane==0){
      size_t base = (size_t)b*VSZ + v0;
      out[base+0] = a0 + bp[v0+0];
      out[base+1] = a1 + bp[v0+1];
      out[base+2] = a2 + bp[v0+2];
      out[base+3] = a3 + bp[v0+3];
    }
  }
}

// ---------------- K9: p_gen + softmax(V) + scale by p_gen, in place ----------------
__global__ __launch_bounds__(256) void k_final(const float* __restrict__ ctxe,
                                               const float* __restrict__ emb,
                                               const float* __restrict__ wc,
                                               const float* __restrict__ wsv,
                                               const float* __restrict__ wy,
                                               const float* __restrict__ pgb,
                                               float* __restrict__ out,
                                               float* __restrict__ pgen_ws){
  __shared__ float red[8];
  int b = blockIdx.x, tid = threadIdx.x, lane = tid & 63, w = tid >> 6;
  const float* hn = out + (size_t)BB*VSZ + (size_t)b*HIDD;
  float acc = 0.f;
  #pragma unroll
  for (int i=0;i<4;i++){ int d=i*256+tid; acc += ctxe[(size_t)b*HIDD+d]*wc[d]; }
  #pragma unroll
  for (int i=0;i<4;i++){ int d=i*256+tid; acc += hn[d]*wsv[d]; }
  #pragma unroll
  for (int i=0;i<2;i++){ int d=i*256+tid; acc += emb[(size_t)b*EMBD+d]*wy[d]; }
  acc = wave_sum(acc);
  if (lane==0) red[w] = acc;
  __syncthreads();
  float pg = sigmoid_f(red[0]+red[1]+red[2]+red[3] + pgb[0]);
  if (tid==0) pgen_ws[b] = pg;
  __syncthreads();

  float* row = out + (size_t)b*VSZ;
  float m = -3.4e38f;
  for (int i=tid;i<VSZ;i+=256) m = fmaxf(m, row[i]);
  m = wave_max(m);
  if (lane==0) red[w] = m;
  __syncthreads();
  m = fmaxf(fmaxf(red[0],red[1]), fmaxf(red[2],red[3]));
  float s = 0.f;
  for (int i=tid;i<VSZ;i+=256) s += __expf(row[i]-m);
  s = wave_sum(s);
  if (lane==0) red[4+w] = s;
  __syncthreads();
  s = red[4]+red[5]+red[6]+red[7];
  float scale = pg / s;
  for (int i=tid;i<VSZ;i+=256) row[i] = __expf(row[i]-m)*scale;
}

// ---------------- K10: pointer scatter ----------------
__global__ __launch_bounds__(256) void k_scatter(const int* __restrict__ src_ids,
                                                 const float* __restrict__ att_e,
                                                 const float* __restrict__ pgen_ws,
                                                 float* __restrict__ out){
  int id = blockIdx.x*256 + threadIdx.x;        // 32768
  int b = id >> 9;
  float pg = pgen_ws[b];
  int sid = src_ids[id];
  float contrib = (1.0f - pg) * att_e[id] * (sid < VSZ ? 1.0f : 0.0f);
  int safe = sid < VSZ-1 ? sid : VSZ-1;
  atomicAdd(&out[(size_t)b*VSZ + safe], contrib);
}

extern "C" void kernel_launch(void* const* d_in, const int* in_sizes, int n_in,
                              void* d_out, int out_size, void* d_ws, size_t ws_size,
                              hipStream_t stream){
  const int*   y     = (const int*)d_in[0];
  const float* h     = (const float*)d_in[1];
  const float* c     = (const float*)d_in[2];
  const float* enc   = (const float*)d_in[3];
  const float* bwd   = (const float*)d_in[4];
  const int*   sids  = (const int*)d_in[5];
  const int*   smask = (const int*)d_in[6];
  const float* tab   = (const float*)d_in[7];
  const float* W_ih  = (const float*)d_in[8];
  const float* W_hh  = (const float*)d_in[9];
  const float* b_ih  = (const float*)d_in[10];
  const float* b_hh  = (const float*)d_in[11];
  const float* Wq_e  = (const float*)d_in[12];
  const float* Wk_e  = (const float*)d_in[13];
  const float* v_e   = (const float*)d_in[14];
  const float* Wq_b  = (const float*)d_in[15];
  const float* Wk_b  = (const float*)d_in[16];
  const float* v_b   = (const float*)d_in[17];
  const float* Wp    = (const float*)d_in[18];
  const float* bp    = (const float*)d_in[19];
  const float* wc    = (const float*)d_in[20];
  const float* wsv   = (const float*)d_in[21];
  const float* wy    = (const float*)d_in[22];
  const float* pgb   = (const float*)d_in[23];
  float* out = (float*)d_out;

  float* W = (float*)d_ws;
  float* ws_emb  = W; W += BB*EMBD;        // 32768
  float* ws_qe   = W; W += BB*HIDD;        // 65536
  float* ws_qb   = W; W += BB*HIDD;        // 65536
  float* ws_atte = W; W += BB*TSEQ;        // 32768
  float* ws_attb = W; W += BB*TSEQ;        // 32768
  float* ws_ctxe = W; W += BB*HIDD;        // 65536
  float* ws_ctxb = W; W += BB*HIDD;        // 65536
  float* ws_ctxp = W; W += 2*BB*8*1024;    // 1048576
  float* ws_gate = W; W += BB*G4;          // 262144
  float* ws_pgen = W; W += BB;             // 64

  k_embed<<<BB, 128, 0, stream>>>(y, tab, ws_emb);
  k_qproj<<<32768, 256, 0, stream>>>(h, Wq_e, Wq_b, ws_qe, ws_qb);
  k_energy<<<dim3(32,BB), 256, 0, stream>>>(enc, Wk_e, ws_qe, v_e, smask, ws_atte);
  k_energy<<<dim3(32,BB), 256, 0, stream>>>(bwd, Wk_b, ws_qb, v_b, nullptr, ws_attb);
  k_softmax_t<<<dim3(BB,2), 256, 0, stream>>>(ws_atte, ws_attb);
  k_ctx<<<dim3(BB,2,8), 256, 0, stream>>>(enc, bwd, ws_atte, ws_attb, ws_ctxp);
  k_ctxred<<<512, 256, 0, stream>>>(ws_ctxp, ws_ctxe, ws_ctxb);
  k_gates<<<65536, 256, 0, stream>>>(ws_emb, ws_ctxe, ws_ctxb, h, W_ih, W_hh, b_ih, b_hh, ws_gate);
  k_lstm<<<256, 256, 0, stream>>>(ws_gate, c, out);
  k_vocab<<<2000, 256, 0, stream>>>(out + (size_t)BB*VSZ, Wp, bp, out);
  k_final<<<BB, 256, 0, stream>>>(ws_ctxe, ws_emb, wc, wsv, wy, pgb, out, ws_pgen);
  k_scatter<<<128, 256, 0, stream>>>(sids, ws_atte, ws_pgen, out);
}

// Round 2
// 866.409 us; speedup vs baseline: 8.1374x; 8.1374x over previous
//
#include <hip/hip_runtime.h>
#include <hip/hip_bf16.h>

#define VSZ   32000
#define EMBD  512
#define HIDD  1024
#define BB    64
#define TSEQ  512
#define G4    4096

typedef short bf16x8 __attribute__((ext_vector_type(8)));
typedef float f32x4  __attribute__((ext_vector_type(4)));
typedef float f32x16 __attribute__((ext_vector_type(16)));

__device__ __forceinline__ float sigmoid_f(float x){ return 1.0f/(1.0f+__expf(-x)); }
__device__ __forceinline__ float fast_tanh(float x){
  float e = __expf(2.0f*x);
  return 1.0f - 2.0f*__builtin_amdgcn_rcpf(e + 1.0f);
}
__device__ __forceinline__ short f2bfs(float x){
  unsigned u = __float_as_uint(x);
  unsigned r = (u + 0x7FFFu + ((u>>16)&1u)) >> 16;
  return (short)r;
}
__device__ __forceinline__ float wave_sum(float x){
  #pragma unroll
  for (int off=32; off>0; off>>=1) x += __shfl_xor(x, off);
  return x;
}
__device__ __forceinline__ float wave_max(float x){
  #pragma unroll
  for (int off=32; off>0; off>>=1) x = fmaxf(x, __shfl_xor(x, off));
  return x;
}

// ---------------- K1: embedding gather ----------------
__global__ __launch_bounds__(128) void k_embed(const int* __restrict__ y,
                                               const float* __restrict__ tab,
                                               float* __restrict__ emb){
  int b = blockIdx.x;
  int row = y[b];
  const float4* src = (const float4*)(tab + (size_t)row*EMBD);
  float4* dst = (float4*)(emb + (size_t)b*EMBD);
  dst[threadIdx.x] = src[threadIdx.x];
}

// ---------------- f32 -> bf16 bulk convert ----------------
__global__ __launch_bounds__(256) void k_cvt(const float* __restrict__ src,
                                             short* __restrict__ dst, int n8){
  int id = blockIdx.x*256 + threadIdx.x;
  if (id >= n8) return;
  const float4* s = (const float4*)(src + (size_t)id*8);
  float4 f0 = s[0], f1 = s[1];
  bf16x8 p;
  p[0]=f2bfs(f0.x); p[1]=f2bfs(f0.y); p[2]=f2bfs(f0.z); p[3]=f2bfs(f0.w);
  p[4]=f2bfs(f1.x); p[5]=f2bfs(f1.y); p[6]=f2bfs(f1.z); p[7]=f2bfs(f1.w);
  *(bf16x8*)(dst + (size_t)id*8) = p;
}

// ---------------- prep: x_bf16[:,2560:3584] = bf16(h) ----------------
__global__ __launch_bounds__(256) void k_prep_h(const float* __restrict__ h,
                                                short* __restrict__ xb){
  int id = blockIdx.x*256 + threadIdx.x;     // 8192
  int b = id >> 7, d = (id & 127)*8;
  const float4* s = (const float4*)(h + (size_t)b*HIDD + d);
  float4 f0 = s[0], f1 = s[1];
  bf16x8 p;
  p[0]=f2bfs(f0.x); p[1]=f2bfs(f0.y); p[2]=f2bfs(f0.z); p[3]=f2bfs(f0.w);
  p[4]=f2bfs(f1.x); p[5]=f2bfs(f1.y); p[6]=f2bfs(f1.z); p[7]=f2bfs(f1.w);
  *(bf16x8*)(xb + (size_t)b*3584 + 2560 + d) = p;
}

// ---------------- prep: x_bf16[:,0:2560] = bf16(emb|ctxe|ctxb) ----------------
__global__ __launch_bounds__(256) void k_prep_x2(const float* __restrict__ emb,
                                                 const float* __restrict__ ctxe,
                                                 const float* __restrict__ ctxb,
                                                 short* __restrict__ xb){
  int id = blockIdx.x*256 + threadIdx.x;     // 20480
  if (id >= 64*320) return;
  int b = id / 320, off = (id % 320)*8;
  const float* src;
  if (off < 512)        src = emb  + (size_t)b*EMBD + off;
  else if (off < 1536)  src = ctxe + (size_t)b*HIDD + (off-512);
  else                  src = ctxb + (size_t)b*HIDD + (off-1536);
  float4 f0 = ((const float4*)src)[0], f1 = ((const float4*)src)[1];
  bf16x8 p;
  p[0]=f2bfs(f0.x); p[1]=f2bfs(f0.y); p[2]=f2bfs(f0.z); p[3]=f2bfs(f0.w);
  p[4]=f2bfs(f1.x); p[5]=f2bfs(f1.y); p[6]=f2bfs(f1.z); p[7]=f2bfs(f1.w);
  *(bf16x8*)(xb + (size_t)b*3584 + off) = p;
}

// ---------------- generic M=64 MFMA GEMM with K-split partials ----------------
// z selects phase set. out_partial[kz][64][ldo]. B is f32 (converted in-reg).
__global__ __launch_bounds__(256) void k_mm64(
    const short* __restrict__ A0, int lda0, const float* __restrict__ B0, int ldb0, int K0, float* __restrict__ out0, int ldo0,
    const short* __restrict__ A1, int lda1, const float* __restrict__ B1, int ldb1, int K1, float* __restrict__ out1, int ldo1){
  const short* A; const float* B; float* out; int lda, ldb, K, ldo;
  if (blockIdx.z == 0){ A=A0; B=B0; out=out0; lda=lda0; ldb=ldb0; K=K0; ldo=ldo0; }
  else                { A=A1; B=B1; out=out1; lda=lda1; ldb=ldb1; K=K1; ldo=ldo1; }
  int tid = threadIdx.x, l = tid & 63, w = tid >> 6;
  int l15 = l & 15, l4 = l >> 4;
  int n0 = blockIdx.x*256 + w*64;
  int kper = K / gridDim.y;
  int dbeg = blockIdx.y * kper, dend = dbeg + kper;
  f32x4 acc[4][4];
  #pragma unroll
  for (int i=0;i<4;i++)
    #pragma unroll
    for (int j=0;j<4;j++)
      #pragma unroll
      for (int r=0;r<4;r++) acc[i][j][r]=0.f;
  for (int d0=dbeg; d0<dend; d0+=32){
    bf16x8 af[4];
    #pragma unroll
    for (int ms=0; ms<4; ms++)
      af[ms] = *(const bf16x8*)(A + (size_t)(ms*16 + l15)*lda + d0 + l4*8);
    bf16x8 bfr[4];
    #pragma unroll
    for (int ni=0; ni<4; ni++){
      const float* bp = B + (size_t)(n0 + ni*16 + l15)*ldb + d0 + l4*8;
      float4 f0 = ((const float4*)bp)[0], f1 = ((const float4*)bp)[1];
      bf16x8 bb;
      bb[0]=f2bfs(f0.x); bb[1]=f2bfs(f0.y); bb[2]=f2bfs(f0.z); bb[3]=f2bfs(f0.w);
      bb[4]=f2bfs(f1.x); bb[5]=f2bfs(f1.y); bb[6]=f2bfs(f1.z); bb[7]=f2bfs(f1.w);
      bfr[ni]=bb;
    }
    #pragma unroll
    for (int ms=0; ms<4; ms++)
      #pragma unroll
      for (int ni=0; ni<4; ni++)
        acc[ms][ni] = __builtin_amdgcn_mfma_f32_16x16x32_bf16(af[ms], bfr[ni], acc[ms][ni], 0,0,0);
  }
  float* op = out + (size_t)blockIdx.y * 64 * ldo;
  #pragma unroll
  for (int ms=0; ms<4; ms++)
    #pragma unroll
    for (int ni=0; ni<4; ni++)
      #pragma unroll
      for (int r=0; r<4; r++){
        int m = ms*16 + l4*4 + r;
        op[(size_t)m*ldo + n0 + ni*16 + l15] = acc[ms][ni][r];
      }
}

// ---------------- qproj partial reduce (2 slots each) ----------------
__global__ __launch_bounds__(256) void k_qred(const float* __restrict__ qpe,
                                              const float* __restrict__ qpb,
                                              float* __restrict__ qe,
                                              float* __restrict__ qb){
  int id = blockIdx.x*256 + threadIdx.x;    // 131072
  int sel = id >> 16, i = id & 65535;
  const float* p = (sel ? qpb : qpe) + i;
  (sel ? qb : qe)[i] = p[0] + p[65536];
}

// ---------------- K3: fused attention energy via MFMA 32x32x16 ----------------
// e[b,t] = v . tanh(q[b] + Wk @ keys[b,t]); grid (8 t-tiles, 64 b, 2 att), 512 thr.
__global__ __launch_bounds__(512) void k_energy(
    const float* __restrict__ enc, const float* __restrict__ bwd,
    const short* __restrict__ wke, const short* __restrict__ wkb,
    const float* __restrict__ qe_, const float* __restrict__ qb_,
    const float* __restrict__ ve, const float* __restrict__ vb,
    const int* __restrict__ mask,
    float* __restrict__ out_e, float* __restrict__ out_b){
  __shared__ short A_s[64*1024];            // 128 KB, XOR-swizzled
  __shared__ float ebuf[8][64];
  int att = blockIdx.z;
  const float* keys = att ? bwd : enc;
  const short* Wk   = att ? wkb : wke;
  const float* q    = att ? qb_ : qe_;
  const float* v    = att ? vb  : ve;
  int b = blockIdx.y, t0 = blockIdx.x*64;
  int tid = threadIdx.x;

  { // stage 64 rows x 1024 d of keys as bf16, swizzled: byte ^= ((row&7)<<4)
    int r = tid >> 3, cb = tid & 7;
    const float* src = keys + ((size_t)(b*TSEQ + t0 + r))*1024 + cb*8;
    char* wb = (char*)A_s + r*2048 + (((cb<<4) ^ ((r&7)<<4)));
    #pragma unroll
    for (int i=0;i<16;i++){
      float4 f0 = ((const float4*)(src + i*64))[0];
      float4 f1 = ((const float4*)(src + i*64))[1];
      bf16x8 p;
      p[0]=f2bfs(f0.x); p[1]=f2bfs(f0.y); p[2]=f2bfs(f0.z); p[3]=f2bfs(f0.w);
      p[4]=f2bfs(f1.x); p[5]=f2bfs(f1.y); p[6]=f2bfs(f1.z); p[7]=f2bfs(f1.w);
      *(bf16x8*)(wb + (i<<7)) = p;
    }
  }
  __syncthreads();

  int l = tid & 63, w = tid >> 6;
  int lhi = l >> 5, l31 = l & 31;
  const short* wrow0 = Wk + (size_t)(w*128 +  0 + l31)*1024 + lhi*8;
  const short* wrow1 = Wk + (size_t)(w*128 + 32 + l31)*1024 + lhi*8;
  const short* wrow2 = Wk + (size_t)(w*128 + 64 + l31)*1024 + lhi*8;
  const short* wrow3 = Wk + (size_t)(w*128 + 96 + l31)*1024 + lhi*8;
  int rb0 = l31*2048, rb1 = (l31+32)*2048;
  int xorv = (l31&7)<<4, boff = lhi*16;

  f32x16 acc0[4], acc1[4];
  #pragma unroll
  for (int at=0; at<4; at++)
    #pragma unroll
    for (int r=0;r<16;r++){ acc0[at][r]=0.f; acc1[at][r]=0.f; }

  for (int d0=0; d0<1024; d0+=16){
    int sw = ((d0*2 + boff) ^ xorv);
    bf16x8 a0 = *(const bf16x8*)((char*)A_s + rb0 + sw);
    bf16x8 a1 = *(const bf16x8*)((char*)A_s + rb1 + sw);
    bf16x8 b0 = *(const bf16x8*)(wrow0 + d0);
    bf16x8 b1 = *(const bf16x8*)(wrow1 + d0);
    bf16x8 b2 = *(const bf16x8*)(wrow2 + d0);
    bf16x8 b3 = *(const bf16x8*)(wrow3 + d0);
    acc0[0] = __builtin_amdgcn_mfma_f32_32x32x16_bf16(a0, b0, acc0[0], 0,0,0);
    acc1[0] = __builtin_amdgcn_mfma_f32_32x32x16_bf16(a1, b0, acc1[0], 0,0,0);
    acc0[1] = __builtin_amdgcn_mfma_f32_32x32x16_bf16(a0, b1, acc0[1], 0,0,0);
    acc1[1] = __builtin_amdgcn_mfma_f32_32x32x16_bf16(a1, b1, acc1[1], 0,0,0);
    acc0[2] = __builtin_amdgcn_mfma_f32_32x32x16_bf16(a0, b2, acc0[2], 0,0,0);
    acc1[2] = __builtin_amdgcn_mfma_f32_32x32x16_bf16(a1, b2, acc1[2], 0,0,0);
    acc0[3] = __builtin_amdgcn_mfma_f32_32x32x16_bf16(a0, b3, acc0[3], 0,0,0);
    acc1[3] = __builtin_amdgcn_mfma_f32_32x32x16_bf16(a1, b3, acc1[3], 0,0,0);
  }

  // fused tanh + v-weighted partial reduction over this wave's 128 a's
  float ep0[16], ep1[16];
  #pragma unroll
  for (int r=0;r<16;r++){ ep0[r]=0.f; ep1[r]=0.f; }
  #pragma unroll
  for (int at=0; at<4; at++){
    int a = w*128 + at*32 + l31;
    float qv = q[(size_t)b*HIDD + a];
    float vv = v[a];
    #pragma unroll
    for (int r=0;r<16;r++){
      ep0[r] += vv * fast_tanh(qv + acc0[at][r]);
      ep1[r] += vv * fast_tanh(qv + acc1[at][r]);
    }
  }
  #pragma unroll
  for (int r=0;r<16;r++){
    float x = ep0[r];
    x += __shfl_xor(x,1); x += __shfl_xor(x,2); x += __shfl_xor(x,4);
    x += __shfl_xor(x,8); x += __shfl_xor(x,16);
    ep0[r] = x;
    float y = ep1[r];
    y += __shfl_xor(y,1); y += __shfl_xor(y,2); y += __shfl_xor(y,4);
    y += __shfl_xor(y,8); y += __shfl_xor(y,16);
    ep1[r] = y;
  }
  if (l31 == 0){
    #pragma unroll
    for (int r=0;r<16;r++){
      int t = (r&3) + 8*(r>>2) + 4*lhi;
      ebuf[w][t]      = ep0[r];
      ebuf[w][t + 32] = ep1[r];
    }
  }
  __syncthreads();
  if (tid < 64){
    float s = 0.f;
    #pragma unroll
    for (int ww=0; ww<8; ww++) s += ebuf[ww][tid];
    int t = t0 + tid;
    if (att==0 && mask[(size_t)b*TSEQ + t]==0) s = -3.4e38f;
    (att ? out_b : out_e)[(size_t)b*TSEQ + t] = s;
  }
}

// ---------------- K4: softmax over T ----------------
__global__ __launch_bounds__(256) void k_softmax_t(float* __restrict__ e_enc,
                                                   float* __restrict__ e_bwd){
  float* e = (blockIdx.y==0 ? e_enc : e_bwd) + (size_t)blockIdx.x*TSEQ;
  __shared__ float red[8];
  int tid = threadIdx.x, lane = tid & 63, w = tid >> 6;
  float v0 = e[tid], v1 = e[tid+256];
  float m = wave_max(fmaxf(v0, v1));
  if (lane==0) red[w] = m;
  __syncthreads();
  m = fmaxf(fmaxf(red[0],red[1]), fmaxf(red[2],red[3]));
  float x0 = __expf(v0-m), x1 = __expf(v1-m);
  float s = wave_sum(x0+x1);
  if (lane==0) red[4+w] = s;
  __syncthreads();
  s = red[4]+red[5]+red[6]+red[7];
  float inv = 1.0f/s;
  e[tid] = x0*inv; e[tid+256] = x1*inv;
}

// ---------------- K5: context = attn @ keys ----------------
__global__ __launch_bounds__(256) void k_ctx(const float* __restrict__ enc,
                                             const float* __restrict__ bwdst,
                                             const float* __restrict__ att_e,
                                             const float* __restrict__ att_b,
                                             float* __restrict__ ctxp){
  int b = blockIdx.x, sel = blockIdx.y, s = blockIdx.z;
  const float* keys = (sel ? bwdst : enc) + ((size_t)b*TSEQ + s*64)*1024;
  const float* att  = (sel ? att_b : att_e) + (size_t)b*TSEQ + s*64;
  int tid = threadIdx.x;
  float acc[4] = {0.f,0.f,0.f,0.f};
  for (int t=0;t<64;t++){
    float a = att[t];
    #pragma unroll
    for (int i=0;i<4;i++) acc[i] += a*keys[(size_t)t*1024 + i*256 + tid];
  }
  float* o = ctxp + (((size_t)sel*BB + b)*8 + s)*1024;
  #pragma unroll
  for (int i=0;i<4;i++) o[i*256+tid] = acc[i];
}

__global__ __launch_bounds__(256) void k_ctxred(const float* __restrict__ ctxp,
                                                float* __restrict__ ctx_e,
                                                float* __restrict__ ctx_b){
  int id = blockIdx.x*256 + threadIdx.x;
  int sel = id >> 16; int rem = id & 65535; int b = rem >> 10; int d = rem & 1023;
  const float* p = ctxp + (((size_t)sel*BB + b)*8)*1024 + d;
  float s = 0.f;
  #pragma unroll
  for (int i=0;i<8;i++) s += p[i*1024];
  (sel ? ctx_b : ctx_e)[(size_t)b*HIDD + d] = s;
}

// ---------------- K7: LSTM cell (fused gates-partial reduce) ----------------
__global__ __launch_bounds__(256) void k_lstm(const float* __restrict__ gp,
                                              const float* __restrict__ b_ih,
                                              const float* __restrict__ b_hh,
                                              const float* __restrict__ c_old,
                                              float* __restrict__ out){
  int id = blockIdx.x*256 + threadIdx.x;    // 65536
  int b = id >> 10, j = id & 1023;
  size_t base = (size_t)b*G4;
  float gs[4];
  #pragma unroll
  for (int g=0; g<4; g++){
    int col = g*1024 + j;
    float s = b_ih[col] + b_hh[col];
    #pragma unroll
    for (int k=0;k<4;k++) s += gp[(size_t)k*(64*G4) + base + col];
    gs[g] = s;
  }
  float ig = sigmoid_f(gs[0]);
  float fg = sigmoid_f(gs[1]);
  float gg = tanhf(gs[2]);
  float og = sigmoid_f(gs[3]);
  float cn = fg*c_old[id] + ig*gg;
  float hn = og*tanhf(cn);
  out[(size_t)BB*VSZ + id] = hn;
  out[(size_t)BB*VSZ + (size_t)BB*HIDD + id] = cn;
}

// ---------------- K8: vocab logits ----------------
__global__ __launch_bounds__(256) void k_vocab(const float* __restrict__ hn_src,
                                               const float* __restrict__ Wp,
                                               const float* __restrict__ bp,
                                               float* __restrict__ out){
  __shared__ __hip_bfloat16 h_s[BB*HIDD];
  int tid = threadIdx.x;
  for (int i=0;i<256;i++) h_s[i*256+tid] = __float2bfloat16(hn_src[i*256+tid]);
  __syncthreads();
  int w = tid>>6, lane = tid&63;
  int v0 = blockIdx.x*16 + w*4;
  float rf[4][16];
  #pragma unroll
  for (int aa=0;aa<4;aa++){
    const float* row = Wp + (size_t)(v0+aa)*HIDD;
    #pragma unroll
    for (int i=0;i<16;i++) rf[aa][i] = row[lane + i*64];
  }
  for (int b=0;b<BB;b++){
    float a0=0.f,a1=0.f,a2=0.f,a3=0.f;
    #pragma unroll
    for (int i=0;i<16;i++){
      float hv = __bfloat162float(h_s[b*HIDD + lane + i*64]);
      a0 += rf[0][i]*hv; a1 += rf[1][i]*hv; a2 += rf[2][i]*hv; a3 += rf[3][i]*hv;
    }
    #pragma unroll
    for (int off=32; off>0; off>>=1){
      a0 += __shfl_xor(a0,off); a1 += __shfl_xor(a1,off);
      a2 += __shfl_xor(a2,off); a3 += __shfl_xor(a3,off);
    }
    if (lane==0){
      size_t base = (size_t)b*VSZ + v0;
      out[base+0] = a0 + bp[v0+0];
      out[base+1] = a1 + bp[v0+1];
      out[base+2] = a2 + bp[v0+2];
      out[base+3] = a3 + bp[v0+3];
    }
  }
}

// ---------------- K9: p_gen + softmax(V) ----------------
__global__ __launch_bounds__(256) void k_final(const float* __restrict__ ctxe,
                                               const float* __restrict__ emb,
                                               const float* __restrict__ wc,
                                               const float* __restrict__ wsv,
                                               const float* __restrict__ wy,
                                               const float* __restrict__ pgb,
                                               float* __restrict__ out,
                                               float* __restrict__ pgen_ws){
  __shared__ float red[8];
  int b = blockIdx.x, tid = threadIdx.x, lane = tid & 63, w = tid >> 6;
  const float* hn = out + (size_t)BB*VSZ + (size_t)b*HIDD;
  float acc = 0.f;
  #pragma unroll
  for (int i=0;i<4;i++){ int d=i*256+tid; acc += ctxe[(size_t)b*HIDD+d]*wc[d]; }
  #pragma unroll
  for (int i=0;i<4;i++){ int d=i*256+tid; acc += hn[d]*wsv[d]; }
  #pragma unroll
  for (int i=0;i<2;i++){ int d=i*256+tid; acc += emb[(size_t)b*EMBD+d]*wy[d]; }
  acc = wave_sum(acc);
  if (lane==0) red[w] = acc;
  __syncthreads();
  float pg = sigmoid_f(red[0]+red[1]+red[2]+red[3] + pgb[0]);
  if (tid==0) pgen_ws[b] = pg;
  __syncthreads();

  float* row = out + (size_t)b*VSZ;
  float m = -3.4e38f;
  for (int i=tid;i<VSZ;i+=256) m = fmaxf(m, row[i]);
  m = wave_max(m);
  if (lane==0) red[w] = m;
  __syncthreads();
  m = fmaxf(fmaxf(red[0],red[1]), fmaxf(red[2],red[3]));
  float s = 0.f;
  for (int i=tid;i<VSZ;i+=256) s += __expf(row[i]-m);
  s = wave_sum(s);
  if (lane==0) red[4+w] = s;
  __syncthreads();
  s = red[4]+red[5]+red[6]+red[7];
  float scale = pg / s;
  for (int i=tid;i<VSZ;i+=256) row[i] = __expf(row[i]-m)*scale;
}

// ---------------- K10: pointer scatter ----------------
__global__ __launch_bounds__(256) void k_scatter(const int* __restrict__ src_ids,
                                                 const float* __restrict__ att_e,
                                                 const float* __restrict__ pgen_ws,
                                                 float* __restrict__ out){
  int id = blockIdx.x*256 + threadIdx.x;
  int b = id >> 9;
  float pg = pgen_ws[b];
  int sid = src_ids[id];
  float contrib = (1.0f - pg) * att_e[id] * (sid < VSZ ? 1.0f : 0.0f);
  int safe = sid < VSZ-1 ? sid : VSZ-1;
  atomicAdd(&out[(size_t)b*VSZ + safe], contrib);
}

extern "C" void kernel_launch(void* const* d_in, const int* in_sizes, int n_in,
                              void* d_out, int out_size, void* d_ws, size_t ws_size,
                              hipStream_t stream){
  const int*   y     = (const int*)d_in[0];
  const float* h     = (const float*)d_in[1];
  const float* c     = (const float*)d_in[2];
  const float* enc   = (const float*)d_in[3];
  const float* bwd   = (const float*)d_in[4];
  const int*   sids  = (const int*)d_in[5];
  const int*   smask = (const int*)d_in[6];
  const float* tab   = (const float*)d_in[7];
  const float* W_ih  = (const float*)d_in[8];
  const float* W_hh  = (const float*)d_in[9];
  const float* b_ih  = (const float*)d_in[10];
  const float* b_hh  = (const float*)d_in[11];
  const float* Wq_e  = (const float*)d_in[12];
  const float* Wk_e  = (const float*)d_in[13];
  const float* v_e   = (const float*)d_in[14];
  const float* Wq_b  = (const float*)d_in[15];
  const float* Wk_b  = (const float*)d_in[16];
  const float* v_b   = (const float*)d_in[17];
  const float* Wp    = (const float*)d_in[18];
  const float* bp    = (const float*)d_in[19];
  const float* wc    = (const float*)d_in[20];
  const float* wsv   = (const float*)d_in[21];
  const float* wy    = (const float*)d_in[22];
  const float* pgb   = (const float*)d_in[23];
  float* out = (float*)d_out;

  float* W = (float*)d_ws;
  float* ws_emb  = W; W += BB*EMBD;          // 32768
  float* ws_qe   = W; W += BB*HIDD;          // 65536
  float* ws_qb   = W; W += BB*HIDD;
  float* ws_atte = W; W += BB*TSEQ;          // 32768
  float* ws_attb = W; W += BB*TSEQ;
  float* ws_ctxe = W; W += BB*HIDD;
  float* ws_ctxb = W; W += BB*HIDD;
  float* ws_ctxp = W; W += 2*BB*8*1024;      // 1048576
  float* ws_pgen = W; W += 64;
  float* ws_qpe  = W; W += 2*BB*HIDD;        // 2 K-split slots
  float* ws_qpb  = W; W += 2*BB*HIDD;
  float* ws_gp   = W; W += 4*BB*G4;          // 4 K-split slots
  short* xb      = (short*)W; W += (BB*3584)/2;        // [64][3584] bf16
  short* wke_b   = (short*)W; W += (HIDD*HIDD)/2;      // Wk_e bf16
  short* wkb_b   = (short*)W; W += (HIDD*HIDD)/2;      // Wk_b bf16

  k_embed<<<BB, 128, 0, stream>>>(y, tab, ws_emb);
  k_cvt<<<512, 256, 0, stream>>>(Wk_e, wke_b, 131072);
  k_cvt<<<512, 256, 0, stream>>>(Wk_b, wkb_b, 131072);
  k_prep_h<<<32, 256, 0, stream>>>(h, xb);
  // qproj: q = h @ Wq^T (z=0: enc, z=1: bwd), K=1024 split 2
  k_mm64<<<dim3(4,2,2), 256, 0, stream>>>(
      xb+2560, 3584, Wq_e, 1024, 1024, ws_qpe, 1024,
      xb+2560, 3584, Wq_b, 1024, 1024, ws_qpb, 1024);
  k_qred<<<512, 256, 0, stream>>>(ws_qpe, ws_qpb, ws_qe, ws_qb);
  k_energy<<<dim3(8,BB,2), 512, 0, stream>>>(enc, bwd, wke_b, wkb_b,
      ws_qe, ws_qb, v_e, v_b, smask, ws_atte, ws_attb);
  k_softmax_t<<<dim3(BB,2), 256, 0, stream>>>(ws_atte, ws_attb);
  k_ctx<<<dim3(BB,2,8), 256, 0, stream>>>(enc, bwd, ws_atte, ws_attb, ws_ctxp);
  k_ctxred<<<512, 256, 0, stream>>>(ws_ctxp, ws_ctxe, ws_ctxb);
  k_prep_x2<<<80, 256, 0, stream>>>(ws_emb, ws_ctxe, ws_ctxb, xb);
  // gates: z=0: x@W_ih^T (K=2560 split 2 -> slots 0,1), z=1: h@W_hh^T (K=1024 -> slots 2,3)
  k_mm64<<<dim3(16,2,2), 256, 0, stream>>>(
      xb,      3584, W_ih, 2560, 2560, ws_gp,             G4,
      xb+2560, 3584, W_hh, 1024, 1024, ws_gp + 2*BB*G4,   G4);
  k_lstm<<<256, 256, 0, stream>>>(ws_gp, b_ih, b_hh, c, out);
  k_vocab<<<2000, 256, 0, stream>>>(out + (size_t)BB*VSZ, Wp, bp, out);
  k_final<<<BB, 256, 0, stream>>>(ws_ctxe, ws_emb, wc, wsv, wy, pgb, out, ws_pgen);
  k_scatter<<<128, 256, 0, stream>>>(sids, ws_atte, ws_pgen, out);
}

// Round 3
// 436.831 us; speedup vs baseline: 16.1397x; 1.9834x over previous
//
#include <hip/hip_runtime.h>
#include <hip/hip_bf16.h>

#define VSZ   32000
#define EMBD  512
#define HIDD  1024
#define BB    64
#define TSEQ  512
#define G4    4096

typedef short bf16x8 __attribute__((ext_vector_type(8)));
typedef float f32x4  __attribute__((ext_vector_type(4)));
typedef float f32x16 __attribute__((ext_vector_type(16)));

__device__ __forceinline__ float sigmoid_f(float x){ return 1.0f/(1.0f+__expf(-x)); }
__device__ __forceinline__ float fast_tanh(float x){
  float e = __expf(2.0f*x);
  return 1.0f - 2.0f*__builtin_amdgcn_rcpf(e + 1.0f);
}
__device__ __forceinline__ short f2bfs(float x){
  unsigned u = __float_as_uint(x);
  unsigned r = (u + 0x7FFFu + ((u>>16)&1u)) >> 16;
  return (short)r;
}
__device__ __forceinline__ bf16x8 cvt8(float4 a, float4 b){
  bf16x8 p;
  p[0]=f2bfs(a.x); p[1]=f2bfs(a.y); p[2]=f2bfs(a.z); p[3]=f2bfs(a.w);
  p[4]=f2bfs(b.x); p[5]=f2bfs(b.y); p[6]=f2bfs(b.z); p[7]=f2bfs(b.w);
  return p;
}
__device__ __forceinline__ float wave_sum(float x){
  #pragma unroll
  for (int off=32; off>0; off>>=1) x += __shfl_xor(x, off);
  return x;
}
__device__ __forceinline__ float wave_max(float x){
  #pragma unroll
  for (int off=32; off>0; off>>=1) x = fmaxf(x, __shfl_xor(x, off));
  return x;
}

// ---------------- K1: embedding gather ----------------
__global__ __launch_bounds__(128) void k_embed(const int* __restrict__ y,
                                               const float* __restrict__ tab,
                                               float* __restrict__ emb){
  int b = blockIdx.x;
  int row = y[b];
  const float4* src = (const float4*)(tab + (size_t)row*EMBD);
  float4* dst = (float4*)(emb + (size_t)b*EMBD);
  dst[threadIdx.x] = src[threadIdx.x];
}

// ---------------- pack Wk into MFMA B-fragment order, f32 -> bf16 ----------------
// dst[((nt*64 + s)*64 + l)*8 + j] = Wk[nt*32 + (l&31)][s*16 + (l>>5)*8 + j]
__global__ __launch_bounds__(256) void k_pack(const float* __restrict__ Wk,
                                              short* __restrict__ dst){
  int id = blockIdx.x*256 + threadIdx.x;   // 131072 = 32nt * 64s * 64l
  int l = id & 63, s = (id>>6) & 63, nt = id >> 12;
  const float* src = Wk + (size_t)(nt*32 + (l&31))*1024 + s*16 + (l>>5)*8;
  float4 f0 = ((const float4*)src)[0], f1 = ((const float4*)src)[1];
  *(bf16x8*)(dst + (size_t)id*8) = cvt8(f0, f1);
}

// ---------------- prep: x_bf16[:,2560:3584] = bf16(h) ----------------
__global__ __launch_bounds__(256) void k_prep_h(const float* __restrict__ h,
                                                short* __restrict__ xb){
  int id = blockIdx.x*256 + threadIdx.x;     // 8192
  int b = id >> 7, d = (id & 127)*8;
  const float4* s = (const float4*)(h + (size_t)b*HIDD + d);
  *(bf16x8*)(xb + (size_t)b*3584 + 2560 + d) = cvt8(s[0], s[1]);
}

// ---------------- prep: x_bf16[:,0:2560] = bf16(emb|ctxe|ctxb) ----------------
__global__ __launch_bounds__(256) void k_prep_x2(const float* __restrict__ emb,
                                                 const float* __restrict__ ctxe,
                                                 const float* __restrict__ ctxb,
                                                 short* __restrict__ xb){
  int id = blockIdx.x*256 + threadIdx.x;     // 20480
  if (id >= 64*320) return;
  int b = id / 320, off = (id % 320)*8;
  const float* src;
  if (off < 512)        src = emb  + (size_t)b*EMBD + off;
  else if (off < 1536)  src = ctxe + (size_t)b*HIDD + (off-512);
  else                  src = ctxb + (size_t)b*HIDD + (off-1536);
  float4 f0 = ((const float4*)src)[0], f1 = ((const float4*)src)[1];
  *(bf16x8*)(xb + (size_t)b*3584 + off) = cvt8(f0, f1);
}

// ---------------- generic M=64 MFMA GEMM with K-split partials ----------------
__global__ __launch_bounds__(256) void k_mm64(
    const short* __restrict__ A0, int lda0, const float* __restrict__ B0, int ldb0, int K0, float* __restrict__ out0, int ldo0,
    const short* __restrict__ A1, int lda1, const float* __restrict__ B1, int ldb1, int K1, float* __restrict__ out1, int ldo1){
  const short* A; const float* B; float* out; int lda, ldb, K, ldo;
  if (blockIdx.z == 0){ A=A0; B=B0; out=out0; lda=lda0; ldb=ldb0; K=K0; ldo=ldo0; }
  else                { A=A1; B=B1; out=out1; lda=lda1; ldb=ldb1; K=K1; ldo=ldo1; }
  int tid = threadIdx.x, l = tid & 63, w = tid >> 6;
  int l15 = l & 15, l4 = l >> 4;
  int n0 = blockIdx.x*256 + w*64;
  int kper = K / gridDim.y;
  int dbeg = blockIdx.y * kper, dend = dbeg + kper;
  f32x4 acc[4][4];
  #pragma unroll
  for (int i=0;i<4;i++)
    #pragma unroll
    for (int j=0;j<4;j++)
      #pragma unroll
      for (int r=0;r<4;r++) acc[i][j][r]=0.f;
  for (int d0=dbeg; d0<dend; d0+=32){
    bf16x8 af[4];
    #pragma unroll
    for (int ms=0; ms<4; ms++)
      af[ms] = *(const bf16x8*)(A + (size_t)(ms*16 + l15)*lda + d0 + l4*8);
    bf16x8 bfr[4];
    #pragma unroll
    for (int ni=0; ni<4; ni++){
      const float* bp = B + (size_t)(n0 + ni*16 + l15)*ldb + d0 + l4*8;
      float4 f0 = ((const float4*)bp)[0], f1 = ((const float4*)bp)[1];
      bfr[ni] = cvt8(f0, f1);
    }
    #pragma unroll
    for (int ms=0; ms<4; ms++)
      #pragma unroll
      for (int ni=0; ni<4; ni++)
        acc[ms][ni] = __builtin_amdgcn_mfma_f32_16x16x32_bf16(af[ms], bfr[ni], acc[ms][ni], 0,0,0);
  }
  float* op = out + (size_t)blockIdx.y * 64 * ldo;
  #pragma unroll
  for (int ms=0; ms<4; ms++)
    #pragma unroll
    for (int ni=0; ni<4; ni++)
      #pragma unroll
      for (int r=0; r<4; r++){
        int m = ms*16 + l4*4 + r;
        op[(size_t)m*ldo + n0 + ni*16 + l15] = acc[ms][ni][r];
      }
}

// ---------------- qproj partial reduce ----------------
__global__ __launch_bounds__(256) void k_qred(const float* __restrict__ qpe,
                                              const float* __restrict__ qpb,
                                              float* __restrict__ qe,
                                              float* __restrict__ qb){
  int id = blockIdx.x*256 + threadIdx.x;    // 131072
  int sel = id >> 16, i = id & 65535;
  const float* p = (sel ? qpb : qpe) + i;
  (sel ? qb : qe)[i] = p[0] + p[65536];
}

// ---------------- K3: fused attention energy via MFMA, K-chunked dbuf staging ----------------
__global__ __launch_bounds__(512,2) void k_energy(
    const float* __restrict__ enc, const float* __restrict__ bwd,
    const short* __restrict__ pke, const short* __restrict__ pkb,
    const float* __restrict__ qe_, const float* __restrict__ qb_,
    const float* __restrict__ ve, const float* __restrict__ vb,
    const int* __restrict__ mask,
    float* __restrict__ out_e, float* __restrict__ out_b){
  __shared__ short A_s[2][64*128];          // 2 x 16 KB, XOR-swizzled
  __shared__ float ebuf[8][64];
  int att = blockIdx.z;
  const float* keys = att ? bwd : enc;
  const short* pk   = att ? pkb : pke;
  const float* q    = att ? qb_ : qe_;
  const float* v    = att ? vb  : ve;
  int b = blockIdx.y, t0 = blockIdx.x*64;
  int tid = threadIdx.x;
  int l = tid & 63, w = tid >> 6;
  int lhi = l >> 5, l31 = l & 31;

  // staging: thread (sr = t-row, sf = 16-float chunk) reads 64B coalesced
  int sr = tid >> 3, sf = tid & 7;
  const float4* ssrc = (const float4*)(keys + ((size_t)(b*TSEQ + t0 + sr))*1024 + sf*16);
  char* swb0 = (char*)A_s + sr*256 + ((sf*32)      ^ ((sr&7)<<4));
  char* swb1 = (char*)A_s + sr*256 + ((sf*32 + 16) ^ ((sr&7)<<4));

  const bf16x8* Bp = ((const bf16x8*)pk) + (size_t)(w*4)*64*64 + l;
  int rb0 = l31*256, rb1 = (l31+32)*256;
  int xorv = (l31&7)<<4;

  f32x16 acc0[4], acc1[4];
  #pragma unroll
  for (int at=0; at<4; at++)
    #pragma unroll
    for (int r=0;r<16;r++){ acc0[at][r]=0.f; acc1[at][r]=0.f; }

  float4 st[4];
  // prologue: stage chunk 0, issue loads for chunk 1
  st[0]=ssrc[0]; st[1]=ssrc[1]; st[2]=ssrc[2]; st[3]=ssrc[3];
  *(bf16x8*)(swb0) = cvt8(st[0], st[1]);
  *(bf16x8*)(swb1) = cvt8(st[2], st[3]);
  __syncthreads();
  st[0]=ssrc[32]; st[1]=ssrc[33]; st[2]=ssrc[34]; st[3]=ssrc[35];

  for (int c=0; c<8; ++c){
    const char* base = (const char*)A_s + (c&1)*16384;
    #pragma unroll
    for (int ss=0; ss<8; ++ss){
      int s = c*8 + ss;
      int off = ((ss*32 + lhi*16) ^ xorv);
      bf16x8 a0 = *(const bf16x8*)(base + rb0 + off);
      bf16x8 a1 = *(const bf16x8*)(base + rb1 + off);
      bf16x8 b0 = Bp[(0*64+s)*64];
      bf16x8 b1 = Bp[(1*64+s)*64];
      bf16x8 b2 = Bp[(2*64+s)*64];
      bf16x8 b3 = Bp[(3*64+s)*64];
      acc0[0] = __builtin_amdgcn_mfma_f32_32x32x16_bf16(a0, b0, acc0[0], 0,0,0);
      acc1[0] = __builtin_amdgcn_mfma_f32_32x32x16_bf16(a1, b0, acc1[0], 0,0,0);
      acc0[1] = __builtin_amdgcn_mfma_f32_32x32x16_bf16(a0, b1, acc0[1], 0,0,0);
      acc1[1] = __builtin_amdgcn_mfma_f32_32x32x16_bf16(a1, b1, acc1[1], 0,0,0);
      acc0[2] = __builtin_amdgcn_mfma_f32_32x32x16_bf16(a0, b2, acc0[2], 0,0,0);
      acc1[2] = __builtin_amdgcn_mfma_f32_32x32x16_bf16(a1, b2, acc1[2], 0,0,0);
      acc0[3] = __builtin_amdgcn_mfma_f32_32x32x16_bf16(a0, b3, acc0[3], 0,0,0);
      acc1[3] = __builtin_amdgcn_mfma_f32_32x32x16_bf16(a1, b3, acc1[3], 0,0,0);
    }
    if (c < 7){
      // write-late (T14): st holds chunk c+1, loaded one iteration ago
      char* dst = (char*)A_s + ((c+1)&1)*16384;
      *(bf16x8*)(dst + (swb0 - (char*)A_s)) = cvt8(st[0], st[1]);
      *(bf16x8*)(dst + (swb1 - (char*)A_s)) = cvt8(st[2], st[3]);
      if (c < 6){
        const float4* s4 = ssrc + (c+2)*32;
        st[0]=s4[0]; st[1]=s4[1]; st[2]=s4[2]; st[3]=s4[3];
      }
    }
    __syncthreads();
  }

  // fused tanh + v-weighted partial reduction
  float ep0[16], ep1[16];
  #pragma unroll
  for (int r=0;r<16;r++){ ep0[r]=0.f; ep1[r]=0.f; }
  #pragma unroll
  for (int at=0; at<4; at++){
    int a = w*128 + at*32 + l31;
    float qv = q[(size_t)b*HIDD + a];
    float vv = v[a];
    #pragma unroll
    for (int r=0;r<16;r++){
      ep0[r] += vv * fast_tanh(qv + acc0[at][r]);
      ep1[r] += vv * fast_tanh(qv + acc1[at][r]);
    }
  }
  #pragma unroll
  for (int r=0;r<16;r++){
    float x = ep0[r];
    x += __shfl_xor(x,1); x += __shfl_xor(x,2); x += __shfl_xor(x,4);
    x += __shfl_xor(x,8); x += __shfl_xor(x,16);
    ep0[r] = x;
    float y = ep1[r];
    y += __shfl_xor(y,1); y += __shfl_xor(y,2); y += __shfl_xor(y,4);
    y += __shfl_xor(y,8); y += __shfl_xor(y,16);
    ep1[r] = y;
  }
  if (l31 == 0){
    #pragma unroll
    for (int r=0;r<16;r++){
      int t = (r&3) + 8*(r>>2) + 4*lhi;
      ebuf[w][t]      = ep0[r];
      ebuf[w][t + 32] = ep1[r];
    }
  }
  __syncthreads();
  if (tid < 64){
    float s = 0.f;
    #pragma unroll
    for (int ww=0; ww<8; ww++) s += ebuf[ww][tid];
    int t = t0 + tid;
    if (att==0 && mask[(size_t)b*TSEQ + t]==0) s = -3.4e38f;
    (att ? out_b : out_e)[(size_t)b*TSEQ + t] = s;
  }
}

// ---------------- K4: softmax over T ----------------
__global__ __launch_bounds__(256) void k_softmax_t(float* __restrict__ e_enc,
                                                   float* __restrict__ e_bwd){
  float* e = (blockIdx.y==0 ? e_enc : e_bwd) + (size_t)blockIdx.x*TSEQ;
  __shared__ float red[8];
  int tid = threadIdx.x, lane = tid & 63, w = tid >> 6;
  float v0 = e[tid], v1 = e[tid+256];
  float m = wave_max(fmaxf(v0, v1));
  if (lane==0) red[w] = m;
  __syncthreads();
  m = fmaxf(fmaxf(red[0],red[1]), fmaxf(red[2],red[3]));
  float x0 = __expf(v0-m), x1 = __expf(v1-m);
  float s = wave_sum(x0+x1);
  if (lane==0) red[4+w] = s;
  __syncthreads();
  s = red[4]+red[5]+red[6]+red[7];
  float inv = 1.0f/s;
  e[tid] = x0*inv; e[tid+256] = x1*inv;
}

// ---------------- K5: context = attn @ keys ----------------
__global__ __launch_bounds__(256) void k_ctx(const float* __restrict__ enc,
                                             const float* __restrict__ bwdst,
                                             const float* __restrict__ att_e,
                                             const float* __restrict__ att_b,
                                             float* __restrict__ ctxp){
  int b = blockIdx.x, sel = blockIdx.y, s = blockIdx.z;
  const float* keys = (sel ? bwdst : enc) + ((size_t)b*TSEQ + s*64)*1024;
  const float* att  = (sel ? att_b : att_e) + (size_t)b*TSEQ + s*64;
  int tid = threadIdx.x;
  float acc[4] = {0.f,0.f,0.f,0.f};
  for (int t=0;t<64;t++){
    float a = att[t];
    #pragma unroll
    for (int i=0;i<4;i++) acc[i] += a*keys[(size_t)t*1024 + i*256 + tid];
  }
  float* o = ctxp + (((size_t)sel*BB + b)*8 + s)*1024;
  #pragma unroll
  for (int i=0;i<4;i++) o[i*256+tid] = acc[i];
}

__global__ __launch_bounds__(256) void k_ctxred(const float* __restrict__ ctxp,
                                                float* __restrict__ ctx_e,
                                                float* __restrict__ ctx_b){
  int id = blockIdx.x*256 + threadIdx.x;
  int sel = id >> 16; int rem = id & 65535; int b = rem >> 10; int d = rem & 1023;
  const float* p = ctxp + (((size_t)sel*BB + b)*8)*1024 + d;
  float s = 0.f;
  #pragma unroll
  for (int i=0;i<8;i++) s += p[i*1024];
  (sel ? ctx_b : ctx_e)[(size_t)b*HIDD + d] = s;
}

// ---------------- K7: LSTM cell (8-slot partial reduce) + bf16 h_new ----------------
__global__ __launch_bounds__(256) void k_lstm(const float* __restrict__ gp,
                                              const float* __restrict__ b_ih,
                                              const float* __restrict__ b_hh,
                                              const float* __restrict__ c_old,
                                              float* __restrict__ out,
                                              short* __restrict__ hb){
  int id = blockIdx.x*256 + threadIdx.x;    // 65536
  int b = id >> 10, j = id & 1023;
  size_t base = (size_t)b*G4;
  float gs[4];
  #pragma unroll
  for (int g=0; g<4; g++){
    int col = g*1024 + j;
    float s = b_ih[col] + b_hh[col];
    #pragma unroll
    for (int k=0;k<8;k++) s += gp[(size_t)k*(64*G4) + base + col];
    gs[g] = s;
  }
  float ig = sigmoid_f(gs[0]);
  float fg = sigmoid_f(gs[1]);
  float gg = tanhf(gs[2]);
  float og = sigmoid_f(gs[3]);
  float cn = fg*c_old[id] + ig*gg;
  float hn = og*tanhf(cn);
  out[(size_t)BB*VSZ + id] = hn;
  out[(size_t)BB*VSZ + (size_t)BB*HIDD + id] = cn;
  hb[id] = f2bfs(hn);
}

// ---------------- K8: vocab logits via MFMA ----------------
__global__ __launch_bounds__(256) void k_vocab2(const short* __restrict__ hb,
                                                const float* __restrict__ Wp,
                                                const float* __restrict__ bp,
                                                float* __restrict__ out){
  int tid = threadIdx.x, l = tid & 63, w = tid >> 6;
  int l15 = l & 15, l4 = l >> 4;
  int n0 = blockIdx.x*256 + w*64;
  f32x4 acc[4][4];
  #pragma unroll
  for (int i=0;i<4;i++)
    #pragma unroll
    for (int j=0;j<4;j++)
      #pragma unroll
      for (int r=0;r<4;r++) acc[i][j][r]=0.f;
  for (int d0=0; d0<1024; d0+=32){
    bf16x8 af[4];
    #pragma unroll
    for (int ms=0; ms<4; ms++)
      af[ms] = *(const bf16x8*)(hb + (size_t)(ms*16 + l15)*1024 + d0 + l4*8);
    bf16x8 bfr[4];
    #pragma unroll
    for (int ni=0; ni<4; ni++){
      const float* bpp = Wp + (size_t)(n0 + ni*16 + l15)*1024 + d0 + l4*8;
      float4 f0 = ((const float4*)bpp)[0], f1 = ((const float4*)bpp)[1];
      bfr[ni] = cvt8(f0, f1);
    }
    #pragma unroll
    for (int ms=0; ms<4; ms++)
      #pragma unroll
      for (int ni=0; ni<4; ni++)
        acc[ms][ni] = __builtin_amdgcn_mfma_f32_16x16x32_bf16(af[ms], bfr[ni], acc[ms][ni], 0,0,0);
  }
  #pragma unroll
  for (int ms=0; ms<4; ms++)
    #pragma unroll
    for (int ni=0; ni<4; ni++)
      #pragma unroll
      for (int r=0; r<4; r++){
        int m = ms*16 + l4*4 + r;
        int n = n0 + ni*16 + l15;
        out[(size_t)m*VSZ + n] = acc[ms][ni][r] + bp[n];
      }
}

// ---------------- K9: p_gen + softmax(V), 1024 threads ----------------
__global__ __launch_bounds__(1024) void k_final(const float* __restrict__ ctxe,
                                                const float* __restrict__ emb,
                                                const float* __restrict__ wc,
                                                const float* __restrict__ wsv,
                                                const float* __restrict__ wy,
                                                const float* __restrict__ pgb,
                                                float* __restrict__ out,
                                                float* __restrict__ pgen_ws){
  __shared__ float red[32];
  int b = blockIdx.x, tid = threadIdx.x, lane = tid & 63, w = tid >> 6;  // w 0..15
  const float* hn = out + (size_t)BB*VSZ + (size_t)b*HIDD;
  float acc = ctxe[(size_t)b*HIDD + tid]*wc[tid] + hn[tid]*wsv[tid];
  if (tid < 512) acc += emb[(size_t)b*EMBD + tid]*wy[tid];
  acc = wave_sum(acc);
  if (lane==0) red[w] = acc;
  __syncthreads();
  float s0 = pgb[0];
  #pragma unroll
  for (int i=0;i<16;i++) s0 += red[i];
  float pg = sigmoid_f(s0);
  if (tid==0) pgen_ws[b] = pg;
  __syncthreads();

  float* row = out + (size_t)b*VSZ;
  float m = -3.4e38f;
  for (int i=tid;i<VSZ;i+=1024) m = fmaxf(m, row[i]);
  m = wave_max(m);
  if (lane==0) red[w] = m;
  __syncthreads();
  #pragma unroll
  for (int i=0;i<16;i++) m = fmaxf(m, red[i]);
  float s = 0.f;
  for (int i=tid;i<VSZ;i+=1024) s += __expf(row[i]-m);
  s = wave_sum(s);
  if (lane==0) red[16+w] = s;
  __syncthreads();
  float tot = 0.f;
  #pragma unroll
  for (int i=0;i<16;i++) tot += red[16+i];
  float scale = pg / tot;
  for (int i=tid;i<VSZ;i+=1024) row[i] = __expf(row[i]-m)*scale;
}

// ---------------- K10: pointer scatter ----------------
__global__ __launch_bounds__(256) void k_scatter(const int* __restrict__ src_ids,
                                                 const float* __restrict__ att_e,
                                                 const float* __restrict__ pgen_ws,
                                                 float* __restrict__ out){
  int id = blockIdx.x*256 + threadIdx.x;
  int b = id >> 9;
  float pg = pgen_ws[b];
  int sid = src_ids[id];
  float contrib = (1.0f - pg) * att_e[id] * (sid < VSZ ? 1.0f : 0.0f);
  int safe = sid < VSZ-1 ? sid : VSZ-1;
  atomicAdd(&out[(size_t)b*VSZ + safe], contrib);
}

extern "C" void kernel_launch(void* const* d_in, const int* in_sizes, int n_in,
                              void* d_out, int out_size, void* d_ws, size_t ws_size,
                              hipStream_t stream){
  const int*   y     = (const int*)d_in[0];
  const float* h     = (const float*)d_in[1];
  const float* c     = (const float*)d_in[2];
  const float* enc   = (const float*)d_in[3];
  const float* bwd   = (const float*)d_in[4];
  const int*   sids  = (const int*)d_in[5];
  const int*   smask = (const int*)d_in[6];
  const float* tab   = (const float*)d_in[7];
  const float* W_ih  = (const float*)d_in[8];
  const float* W_hh  = (const float*)d_in[9];
  const float* b_ih  = (const float*)d_in[10];
  const float* b_hh  = (const float*)d_in[11];
  const float* Wq_e  = (const float*)d_in[12];
  const float* Wk_e  = (const float*)d_in[13];
  const float* v_e   = (const float*)d_in[14];
  const float* Wq_b  = (const float*)d_in[15];
  const float* Wk_b  = (const float*)d_in[16];
  const float* v_b   = (const float*)d_in[17];
  const float* Wp    = (const float*)d_in[18];
  const float* bp    = (const float*)d_in[19];
  const float* wc    = (const float*)d_in[20];
  const float* wsv   = (const float*)d_in[21];
  const float* wy    = (const float*)d_in[22];
  const float* pgb   = (const float*)d_in[23];
  float* out = (float*)d_out;

  float* W = (float*)d_ws;
  float* ws_emb  = W; W += BB*EMBD;          // 32768
  float* ws_qe   = W; W += BB*HIDD;
  float* ws_qb   = W; W += BB*HIDD;
  float* ws_atte = W; W += BB*TSEQ;
  float* ws_attb = W; W += BB*TSEQ;
  float* ws_ctxe = W; W += BB*HIDD;
  float* ws_ctxb = W; W += BB*HIDD;
  float* ws_ctxp = W; W += 2*BB*8*1024;      // 1048576
  float* ws_pgen = W; W += 64;
  float* ws_qpe  = W; W += 2*BB*HIDD;
  float* ws_qpb  = W; W += 2*BB*HIDD;
  float* ws_gp   = W; W += 8*BB*G4;          // 2097152 (8 K-split slots)
  short* xb      = (short*)W; W += (BB*3584)/2;
  short* hb      = (short*)W; W += (BB*HIDD)/2;
  short* pk_e    = (short*)W; W += (HIDD*HIDD)/2;   // packed Wk_e bf16
  short* pk_b    = (short*)W; W += (HIDD*HIDD)/2;

  k_embed<<<BB, 128, 0, stream>>>(y, tab, ws_emb);
  k_pack<<<512, 256, 0, stream>>>(Wk_e, pk_e);
  k_pack<<<512, 256, 0, stream>>>(Wk_b, pk_b);
  k_prep_h<<<32, 256, 0, stream>>>(h, xb);
  k_mm64<<<dim3(4,2,2), 256, 0, stream>>>(
      xb+2560, 3584, Wq_e, 1024, 1024, ws_qpe, 1024,
      xb+2560, 3584, Wq_b, 1024, 1024, ws_qpb, 1024);
  k_qred<<<512, 256, 0, stream>>>(ws_qpe, ws_qpb, ws_qe, ws_qb);
  k_energy<<<dim3(8,BB,2), 512, 0, stream>>>(enc, bwd, pk_e, pk_b,
      ws_qe, ws_qb, v_e, v_b, smask, ws_atte, ws_attb);
  k_softmax_t<<<dim3(BB,2), 256, 0, stream>>>(ws_atte, ws_attb);
  k_ctx<<<dim3(BB,2,8), 256, 0, stream>>>(enc, bwd, ws_atte, ws_attb, ws_ctxp);
  k_ctxred<<<512, 256, 0, stream>>>(ws_ctxp, ws_ctxe, ws_ctxb);
  k_prep_x2<<<80, 256, 0, stream>>>(ws_emb, ws_ctxe, ws_ctxb, xb);
  // gates: z=0 x@W_ih^T (K=2560, 4 splits -> slots 0-3); z=1 h@W_hh^T (K=1024, 4 splits -> slots 4-7)
  k_mm64<<<dim3(16,4,2), 256, 0, stream>>>(
      xb,      3584, W_ih, 2560, 2560, ws_gp,             G4,
      xb+2560, 3584, W_hh, 1024, 1024, ws_gp + 4*BB*G4,   G4);
  k_lstm<<<256, 256, 0, stream>>>(ws_gp, b_ih, b_hh, c, out, hb);
  k_vocab2<<<125, 256, 0, stream>>>(hb, Wp, bp, out);
  k_final<<<BB, 1024, 0, stream>>>(ws_ctxe, ws_emb, wc, wsv, wy, pgb, out, ws_pgen);
  k_scatter<<<128, 256, 0, stream>>>(sids, ws_atte, ws_pgen, out);
}

// Round 4
// 432.883 us; speedup vs baseline: 16.2869x; 1.0091x over previous
//
#include <hip/hip_runtime.h>
#include <hip/hip_bf16.h>

#define VSZ   32000
#define EMBD  512
#define HIDD  1024
#define BB    64
#define TSEQ  512
#define G4    4096

typedef short bf16x8 __attribute__((ext_vector_type(8)));
typedef float f32x4  __attribute__((ext_vector_type(4)));
typedef float f32x16 __attribute__((ext_vector_type(16)));

__device__ __forceinline__ float sigmoid_f(float x){ return 1.0f/(1.0f+__expf(-x)); }
__device__ __forceinline__ float fast_tanh(float x){
  float e = __expf(2.0f*x);
  return 1.0f - 2.0f*__builtin_amdgcn_rcpf(e + 1.0f);
}
__device__ __forceinline__ short f2bfs(float x){
  unsigned u = __float_as_uint(x);
  unsigned r = (u + 0x7FFFu + ((u>>16)&1u)) >> 16;
  return (short)r;
}
__device__ __forceinline__ bf16x8 cvt8(float4 a, float4 b){
  bf16x8 p;
  p[0]=f2bfs(a.x); p[1]=f2bfs(a.y); p[2]=f2bfs(a.z); p[3]=f2bfs(a.w);
  p[4]=f2bfs(b.x); p[5]=f2bfs(b.y); p[6]=f2bfs(b.z); p[7]=f2bfs(b.w);
  return p;
}
__device__ __forceinline__ float wave_sum(float x){
  #pragma unroll
  for (int off=32; off>0; off>>=1) x += __shfl_xor(x, off);
  return x;
}
__device__ __forceinline__ float wave_max(float x){
  #pragma unroll
  for (int off=32; off>0; off>>=1) x = fmaxf(x, __shfl_xor(x, off));
  return x;
}

// ---------------- pack Wk into MFMA B-fragment order, f32 -> bf16 ----------------
// dst[((nt*64 + s)*64 + l)*8 + j] = Wk[nt*32 + (l&31)][s*16 + (l>>5)*8 + j]
__global__ __launch_bounds__(256) void k_pack(const float* __restrict__ Wk,
                                              short* __restrict__ dst){
  int id = blockIdx.x*256 + threadIdx.x;   // 131072 = 32nt * 64s * 64l
  int l = id & 63, s = (id>>6) & 63, nt = id >> 12;
  const float* src = Wk + (size_t)(nt*32 + (l&31))*1024 + s*16 + (l>>5)*8;
  float4 f0 = ((const float4*)src)[0], f1 = ((const float4*)src)[1];
  *(bf16x8*)(dst + (size_t)id*8) = cvt8(f0, f1);
}

// ---------------- prep: x_bf16[:,2560:3584] = bf16(h) ----------------
__global__ __launch_bounds__(256) void k_prep_h(const float* __restrict__ h,
                                                short* __restrict__ xb){
  int id = blockIdx.x*256 + threadIdx.x;     // 8192
  int b = id >> 7, d = (id & 127)*8;
  const float4* s = (const float4*)(h + (size_t)b*HIDD + d);
  *(bf16x8*)(xb + (size_t)b*3584 + 2560 + d) = cvt8(s[0], s[1]);
}

// ---------------- prep: x_bf16[:,0:2560] = bf16(emb|ctxe|ctxb), emb gathered ----------------
__global__ __launch_bounds__(256) void k_prep_x2(const float* __restrict__ tab,
                                                 const int* __restrict__ y,
                                                 const float* __restrict__ ctxe,
                                                 const float* __restrict__ ctxb,
                                                 short* __restrict__ xb){
  int id = blockIdx.x*256 + threadIdx.x;     // 20480
  if (id >= 64*320) return;
  int b = id / 320, off = (id % 320)*8;
  const float* src;
  if (off < 512)        src = tab  + (size_t)y[b]*EMBD + off;
  else if (off < 1536)  src = ctxe + (size_t)b*HIDD + (off-512);
  else                  src = ctxb + (size_t)b*HIDD + (off-1536);
  float4 f0 = ((const float4*)src)[0], f1 = ((const float4*)src)[1];
  *(bf16x8*)(xb + (size_t)b*3584 + off) = cvt8(f0, f1);
}

// ---------------- generic M=64 MFMA GEMM with K-split partials ----------------
__global__ __launch_bounds__(256) void k_mm64(
    const short* __restrict__ A0, int lda0, const float* __restrict__ B0, int ldb0, int K0, float* __restrict__ out0, int ldo0,
    const short* __restrict__ A1, int lda1, const float* __restrict__ B1, int ldb1, int K1, float* __restrict__ out1, int ldo1){
  const short* A; const float* B; float* out; int lda, ldb, K, ldo;
  if (blockIdx.z == 0){ A=A0; B=B0; out=out0; lda=lda0; ldb=ldb0; K=K0; ldo=ldo0; }
  else                { A=A1; B=B1; out=out1; lda=lda1; ldb=ldb1; K=K1; ldo=ldo1; }
  int tid = threadIdx.x, l = tid & 63, w = tid >> 6;
  int l15 = l & 15, l4 = l >> 4;
  int n0 = blockIdx.x*256 + w*64;
  int kper = K / gridDim.y;
  int dbeg = blockIdx.y * kper, dend = dbeg + kper;
  f32x4 acc[4][4];
  #pragma unroll
  for (int i=0;i<4;i++)
    #pragma unroll
    for (int j=0;j<4;j++)
      #pragma unroll
      for (int r=0;r<4;r++) acc[i][j][r]=0.f;
  for (int d0=dbeg; d0<dend; d0+=32){
    bf16x8 af[4];
    #pragma unroll
    for (int ms=0; ms<4; ms++)
      af[ms] = *(const bf16x8*)(A + (size_t)(ms*16 + l15)*lda + d0 + l4*8);
    bf16x8 bfr[4];
    #pragma unroll
    for (int ni=0; ni<4; ni++){
      const float* bp = B + (size_t)(n0 + ni*16 + l15)*ldb + d0 + l4*8;
      float4 f0 = ((const float4*)bp)[0], f1 = ((const float4*)bp)[1];
      bfr[ni] = cvt8(f0, f1);
    }
    #pragma unroll
    for (int ms=0; ms<4; ms++)
      #pragma unroll
      for (int ni=0; ni<4; ni++)
        acc[ms][ni] = __builtin_amdgcn_mfma_f32_16x16x32_bf16(af[ms], bfr[ni], acc[ms][ni], 0,0,0);
  }
  float* op = out + (size_t)blockIdx.y * 64 * ldo;
  #pragma unroll
  for (int ms=0; ms<4; ms++)
    #pragma unroll
    for (int ni=0; ni<4; ni++)
      #pragma unroll
      for (int r=0; r<4; r++){
        int m = ms*16 + l4*4 + r;
        op[(size_t)m*ldo + n0 + ni*16 + l15] = acc[ms][ni][r];
      }
}

// ---------------- K3: fused attention energy via MFMA, a-halved blocks ----------------
// grid (32, 64): bx = t0tile*4 + att*2 + half (halves x-adjacent for L2 dedup)
// block 256 thr (4 waves); wave covers M=64t x N=128a of its half. e-partials linear in a.
__global__ __launch_bounds__(256,2) void k_energy(
    const float* __restrict__ enc, const float* __restrict__ bwd,
    const short* __restrict__ pke, const short* __restrict__ pkb,
    const float* __restrict__ qpe, const float* __restrict__ qpb,  // [2][64][1024] partials
    const float* __restrict__ ve, const float* __restrict__ vb,
    float* __restrict__ ep_out){                                   // [att][half][64][512]
  __shared__ short A_s[2][64*128];   // 2 x 16 KB
  __shared__ float ebuf[4][64];
  int bx = blockIdx.x;
  int half = bx & 1, att = (bx>>1) & 1, t0 = (bx>>2)*64;
  const float* keys = att ? bwd : enc;
  const short* pk   = att ? pkb : pke;
  const float* qp   = att ? qpb : qpe;
  const float* v    = att ? vb  : ve;
  int b = blockIdx.y;
  int tid = threadIdx.x, l = tid & 63, w = tid >> 6;
  int lhi = l >> 5, l31 = l & 31;

  // staging: thread sr=tid>>2 (row), sf=tid&3 (128B f32 segment); 8 float4/thread/chunk
  int sr = tid >> 2, sf = tid & 3;
  const float4* ssrc = (const float4*)(keys + ((size_t)(b*TSEQ + t0 + sr))*1024) + sf*8;
  char* swb = (char*)A_s + sr*256;
  int wsw[4];
  #pragma unroll
  for (int j=0;j<4;j++) wsw[j] = (((sf*4+j)<<4) ^ ((sr&15)<<4));

  // B pointer: this wave's 4 nt-tiles start at nt_base = half*16 + w*4
  const bf16x8* Bp = ((const bf16x8*)pk) + ((size_t)(half*16 + w*4)*64)*64 + l;
  int rb0 = l31*256, rb1 = (l31+32)*256;
  int xorv = (l31&15)<<4;

  f32x16 acc0[4], acc1[4];
  #pragma unroll
  for (int at=0; at<4; at++)
    #pragma unroll
    for (int r=0;r<16;r++){ acc0[at][r]=0.f; acc1[at][r]=0.f; }

  float4 st[8];
  // prologue: stage chunk 0, then issue loads for chunk 1
  #pragma unroll
  for (int i=0;i<8;i++) st[i] = ssrc[i];
  #pragma unroll
  for (int j=0;j<4;j++) *(bf16x8*)(swb + wsw[j]) = cvt8(st[2*j], st[2*j+1]);
  __syncthreads();
  #pragma unroll
  for (int i=0;i<8;i++) st[i] = ssrc[32 + i];

  for (int c=0; c<8; ++c){
    const char* base = (const char*)A_s + (c&1)*16384;
    #pragma unroll
    for (int ss=0; ss<8; ++ss){
      int s = c*8 + ss;
      bf16x8 b0 = Bp[(0*64+s)*64];
      bf16x8 b1 = Bp[(1*64+s)*64];
      bf16x8 b2 = Bp[(2*64+s)*64];
      bf16x8 b3 = Bp[(3*64+s)*64];
      int off = (((ss*2 + lhi)<<4) ^ xorv);
      bf16x8 a0 = *(const bf16x8*)(base + rb0 + off);
      bf16x8 a1 = *(const bf16x8*)(base + rb1 + off);
      acc0[0] = __builtin_amdgcn_mfma_f32_32x32x16_bf16(a0, b0, acc0[0], 0,0,0);
      acc1[0] = __builtin_amdgcn_mfma_f32_32x32x16_bf16(a1, b0, acc1[0], 0,0,0);
      acc0[1] = __builtin_amdgcn_mfma_f32_32x32x16_bf16(a0, b1, acc0[1], 0,0,0);
      acc1[1] = __builtin_amdgcn_mfma_f32_32x32x16_bf16(a1, b1, acc1[1], 0,0,0);
      acc0[2] = __builtin_amdgcn_mfma_f32_32x32x16_bf16(a0, b2, acc0[2], 0,0,0);
      acc1[2] = __builtin_amdgcn_mfma_f32_32x32x16_bf16(a1, b2, acc1[2], 0,0,0);
      acc0[3] = __builtin_amdgcn_mfma_f32_32x32x16_bf16(a0, b3, acc0[3], 0,0,0);
      acc1[3] = __builtin_amdgcn_mfma_f32_32x32x16_bf16(a1, b3, acc1[3], 0,0,0);
    }
    if (c < 7){
      // write-late: st holds chunk c+1
      char* dst = (char*)A_s + ((c+1)&1)*16384 + sr*256;
      #pragma unroll
      for (int j=0;j<4;j++) *(bf16x8*)(dst + wsw[j]) = cvt8(st[2*j], st[2*j+1]);
      if (c < 6){
        #pragma unroll
        for (int i=0;i<8;i++) st[i] = ssrc[(c+2)*32 + i];
      }
    }
    __syncthreads();
  }

  // fused tanh + v-weighted partial reduction over this wave's 128 a's
  float ep0[16], ep1[16];
  #pragma unroll
  for (int r=0;r<16;r++){ ep0[r]=0.f; ep1[r]=0.f; }
  #pragma unroll
  for (int at=0; at<4; at++){
    int a = half*512 + w*128 + at*32 + l31;
    float qv = qp[(size_t)b*HIDD + a] + qp[65536 + (size_t)b*HIDD + a];
    float vv = v[a];
    #pragma unroll
    for (int r=0;r<16;r++){
      ep0[r] += vv * fast_tanh(qv + acc0[at][r]);
      ep1[r] += vv * fast_tanh(qv + acc1[at][r]);
    }
  }
  #pragma unroll
  for (int r=0;r<16;r++){
    float x = ep0[r];
    x += __shfl_xor(x,1); x += __shfl_xor(x,2); x += __shfl_xor(x,4);
    x += __shfl_xor(x,8); x += __shfl_xor(x,16);
    ep0[r] = x;
    float y = ep1[r];
    y += __shfl_xor(y,1); y += __shfl_xor(y,2); y += __shfl_xor(y,4);
    y += __shfl_xor(y,8); y += __shfl_xor(y,16);
    ep1[r] = y;
  }
  if (l31 == 0){
    #pragma unroll
    for (int r=0;r<16;r++){
      int t = (r&3) + 8*(r>>2) + 4*lhi;
      ebuf[w][t]      = ep0[r];
      ebuf[w][t + 32] = ep1[r];
    }
  }
  __syncthreads();
  if (tid < 64){
    float s = 0.f;
    #pragma unroll
    for (int ww=0; ww<4; ww++) s += ebuf[ww][tid];
    ep_out[(((size_t)att*2 + half)*BB + b)*TSEQ + t0 + tid] = s;
  }
}

// ---------------- K4: softmax over T (sums the two a-half partials, applies mask) ----------------
__global__ __launch_bounds__(256) void k_softmax_t(const float* __restrict__ ep,
                                                   const int* __restrict__ mask,
                                                   float* __restrict__ att_e,
                                                   float* __restrict__ att_b){
  int b = blockIdx.x, att = blockIdx.y;
  const float* p0 = ep + (((size_t)att*2 + 0)*BB + b)*TSEQ;
  const float* p1 = ep + (((size_t)att*2 + 1)*BB + b)*TSEQ;
  float* e = (att ? att_b : att_e) + (size_t)b*TSEQ;
  __shared__ float red[8];
  int tid = threadIdx.x, lane = tid & 63, w = tid >> 6;
  float v0 = p0[tid] + p1[tid];
  float v1 = p0[tid+256] + p1[tid+256];
  if (att==0){
    if (mask[(size_t)b*TSEQ + tid]==0)      v0 = -3.4e38f;
    if (mask[(size_t)b*TSEQ + tid+256]==0)  v1 = -3.4e38f;
  }
  float m = wave_max(fmaxf(v0, v1));
  if (lane==0) red[w] = m;
  __syncthreads();
  m = fmaxf(fmaxf(red[0],red[1]), fmaxf(red[2],red[3]));
  float x0 = __expf(v0-m), x1 = __expf(v1-m);
  float s = wave_sum(x0+x1);
  if (lane==0) red[4+w] = s;
  __syncthreads();
  s = red[4]+red[5]+red[6]+red[7];
  float inv = 1.0f/s;
  e[tid] = x0*inv; e[tid+256] = x1*inv;
}

// ---------------- K5: context = attn @ keys ----------------
__global__ __launch_bounds__(256) void k_ctx(const float* __restrict__ enc,
                                             const float* __restrict__ bwdst,
                                             const float* __restrict__ att_e,
                                             const float* __restrict__ att_b,
                                             float* __restrict__ ctxp){
  int b = blockIdx.x, sel = blockIdx.y, s = blockIdx.z;
  const float* keys = (sel ? bwdst : enc) + ((size_t)b*TSEQ + s*64)*1024;
  const float* att  = (sel ? att_b : att_e) + (size_t)b*TSEQ + s*64;
  int tid = threadIdx.x;
  float acc[4] = {0.f,0.f,0.f,0.f};
  for (int t=0;t<64;t++){
    float a = att[t];
    #pragma unroll
    for (int i=0;i<4;i++) acc[i] += a*keys[(size_t)t*1024 + i*256 + tid];
  }
  float* o = ctxp + (((size_t)sel*BB + b)*8 + s)*1024;
  #pragma unroll
  for (int i=0;i<4;i++) o[i*256+tid] = acc[i];
}

__global__ __launch_bounds__(256) void k_ctxred(const float* __restrict__ ctxp,
                                                float* __restrict__ ctx_e,
                                                float* __restrict__ ctx_b){
  int id = blockIdx.x*256 + threadIdx.x;
  int sel = id >> 16; int rem = id & 65535; int b = rem >> 10; int d = rem & 1023;
  const float* p = ctxp + (((size_t)sel*BB + b)*8)*1024 + d;
  float s = 0.f;
  #pragma unroll
  for (int i=0;i<8;i++) s += p[i*1024];
  (sel ? ctx_b : ctx_e)[(size_t)b*HIDD + d] = s;
}

// ---------------- K7: LSTM cell (8-slot partial reduce) + bf16 h_new ----------------
__global__ __launch_bounds__(256) void k_lstm(const float* __restrict__ gp,
                                              const float* __restrict__ b_ih,
                                              const float* __restrict__ b_hh,
                                              const float* __restrict__ c_old,
                                              float* __restrict__ out,
                                              short* __restrict__ hb){
  int id = blockIdx.x*256 + threadIdx.x;    // 65536
  int b = id >> 10, j = id & 1023;
  size_t base = (size_t)b*G4;
  float gs[4];
  #pragma unroll
  for (int g=0; g<4; g++){
    int col = g*1024 + j;
    float s = b_ih[col] + b_hh[col];
    #pragma unroll
    for (int k=0;k<8;k++) s += gp[(size_t)k*(64*G4) + base + col];
    gs[g] = s;
  }
  float ig = sigmoid_f(gs[0]);
  float fg = sigmoid_f(gs[1]);
  float gg = tanhf(gs[2]);
  float og = sigmoid_f(gs[3]);
  float cn = fg*c_old[id] + ig*gg;
  float hn = og*tanhf(cn);
  out[(size_t)BB*VSZ + id] = hn;
  out[(size_t)BB*VSZ + (size_t)BB*HIDD + id] = cn;
  hb[id] = f2bfs(hn);
}

// ---------------- K8: vocab logits via MFMA, N=128/block (250 blocks) ----------------
__global__ __launch_bounds__(256) void k_vocab2(const short* __restrict__ hb,
                                                const float* __restrict__ Wp,
                                                const float* __restrict__ bp,
                                                float* __restrict__ out){
  int tid = threadIdx.x, l = tid & 63, w = tid >> 6;
  int l15 = l & 15, l4 = l >> 4;
  int mh = w >> 1;                       // m-half: rows mh*32 .. mh*32+31
  int n0 = blockIdx.x*128 + (w&1)*64;    // 64 n-cols per wave
  f32x4 acc[2][4];
  #pragma unroll
  for (int i=0;i<2;i++)
    #pragma unroll
    for (int j=0;j<4;j++)
      #pragma unroll
      for (int r=0;r<4;r++) acc[i][j][r]=0.f;
  for (int d0=0; d0<1024; d0+=32){
    bf16x8 af[2];
    #pragma unroll
    for (int ms=0; ms<2; ms++)
      af[ms] = *(const bf16x8*)(hb + (size_t)(mh*32 + ms*16 + l15)*1024 + d0 + l4*8);
    bf16x8 bfr[4];
    #pragma unroll
    for (int ni=0; ni<4; ni++){
      const float* bpp = Wp + (size_t)(n0 + ni*16 + l15)*1024 + d0 + l4*8;
      float4 f0 = ((const float4*)bpp)[0], f1 = ((const float4*)bpp)[1];
      bfr[ni] = cvt8(f0, f1);
    }
    #pragma unroll
    for (int ms=0; ms<2; ms++)
      #pragma unroll
      for (int ni=0; ni<4; ni++)
        acc[ms][ni] = __builtin_amdgcn_mfma_f32_16x16x32_bf16(af[ms], bfr[ni], acc[ms][ni], 0,0,0);
  }
  #pragma unroll
  for (int ms=0; ms<2; ms++)
    #pragma unroll
    for (int ni=0; ni<4; ni++)
      #pragma unroll
      for (int r=0; r<4; r++){
        int m = mh*32 + ms*16 + l4*4 + r;
        int n = n0 + ni*16 + l15;
        out[(size_t)m*VSZ + n] = acc[ms][ni][r] + bp[n];
      }
}

// ---------------- K9: p_gen + softmax(V), 1024 threads, emb gathered ----------------
__global__ __launch_bounds__(1024) void k_final(const float* __restrict__ ctxe,
                                                const float* __restrict__ tab,
                                                const int* __restrict__ y,
                                                const float* __restrict__ wc,
                                                const float* __restrict__ wsv,
                                                const float* __restrict__ wy,
                                                const float* __restrict__ pgb,
                                                float* __restrict__ out,
                                                float* __restrict__ pgen_ws){
  __shared__ float red[32];
  int b = blockIdx.x, tid = threadIdx.x, lane = tid & 63, w = tid >> 6;  // w 0..15
  const float* hn = out + (size_t)BB*VSZ + (size_t)b*HIDD;
  float acc = ctxe[(size_t)b*HIDD + tid]*wc[tid] + hn[tid]*wsv[tid];
  if (tid < 512) acc += tab[(size_t)y[b]*EMBD + tid]*wy[tid];
  acc = wave_sum(acc);
  if (lane==0) red[w] = acc;
  __syncthreads();
  float s0 = pgb[0];
  #pragma unroll
  for (int i=0;i<16;i++) s0 += red[i];
  float pg = sigmoid_f(s0);
  if (tid==0) pgen_ws[b] = pg;
  __syncthreads();

  float* row = out + (size_t)b*VSZ;
  float m = -3.4e38f;
  for (int i=tid;i<VSZ;i+=1024) m = fmaxf(m, row[i]);
  m = wave_max(m);
  if (lane==0) red[w] = m;
  __syncthreads();
  #pragma unroll
  for (int i=0;i<16;i++) m = fmaxf(m, red[i]);
  float s = 0.f;
  for (int i=tid;i<VSZ;i+=1024) s += __expf(row[i]-m);
  s = wave_sum(s);
  if (lane==0) red[16+w] = s;
  __syncthreads();
  float tot = 0.f;
  #pragma unroll
  for (int i=0;i<16;i++) tot += red[16+i];
  float scale = pg / tot;
  for (int i=tid;i<VSZ;i+=1024) row[i] = __expf(row[i]-m)*scale;
}

// ---------------- K10: pointer scatter ----------------
__global__ __launch_bounds__(256) void k_scatter(const int* __restrict__ src_ids,
                                                 const float* __restrict__ att_e,
                                                 const float* __restrict__ pgen_ws,
                                                 float* __restrict__ out){
  int id = blockIdx.x*256 + threadIdx.x;
  int b = id >> 9;
  float pg = pgen_ws[b];
  int sid = src_ids[id];
  float contrib = (1.0f - pg) * att_e[id] * (sid < VSZ ? 1.0f : 0.0f);
  int safe = sid < VSZ-1 ? sid : VSZ-1;
  atomicAdd(&out[(size_t)b*VSZ + safe], contrib);
}

extern "C" void kernel_launch(void* const* d_in, const int* in_sizes, int n_in,
                              void* d_out, int out_size, void* d_ws, size_t ws_size,
                              hipStream_t stream){
  const int*   y     = (const int*)d_in[0];
  const float* h     = (const float*)d_in[1];
  const float* c     = (const float*)d_in[2];
  const float* enc   = (const float*)d_in[3];
  const float* bwd   = (const float*)d_in[4];
  const int*   sids  = (const int*)d_in[5];
  const int*   smask = (const int*)d_in[6];
  const float* tab   = (const float*)d_in[7];
  const float* W_ih  = (const float*)d_in[8];
  const float* W_hh  = (const float*)d_in[9];
  const float* b_ih  = (const float*)d_in[10];
  const float* b_hh  = (const float*)d_in[11];
  const float* Wq_e  = (const float*)d_in[12];
  const float* Wk_e  = (const float*)d_in[13];
  const float* v_e   = (const float*)d_in[14];
  const float* Wq_b  = (const float*)d_in[15];
  const float* Wk_b  = (const float*)d_in[16];
  const float* v_b   = (const float*)d_in[17];
  const float* Wp    = (const float*)d_in[18];
  const float* bp    = (const float*)d_in[19];
  const float* wc    = (const float*)d_in[20];
  const float* wsv   = (const float*)d_in[21];
  const float* wy    = (const float*)d_in[22];
  const float* pgb   = (const float*)d_in[23];
  float* out = (float*)d_out;

  float* W = (float*)d_ws;
  float* ws_qpe  = W; W += 2*BB*HIDD;        // qproj partials
  float* ws_qpb  = W; W += 2*BB*HIDD;
  float* ws_ep   = W; W += 4*BB*TSEQ;        // energy partials [att][half][b][t]
  float* ws_atte = W; W += BB*TSEQ;
  float* ws_attb = W; W += BB*TSEQ;
  float* ws_ctxe = W; W += BB*HIDD;
  float* ws_ctxb = W; W += BB*HIDD;
  float* ws_ctxp = W; W += 2*BB*8*1024;      // 1048576
  float* ws_pgen = W; W += 64;
  float* ws_gp   = W; W += 8*BB*G4;          // 2097152 (8 K-split slots)
  short* xb      = (short*)W; W += (BB*3584)/2;
  short* hb      = (short*)W; W += (BB*HIDD)/2;
  short* pk_e    = (short*)W; W += (HIDD*HIDD)/2;   // packed Wk_e bf16
  short* pk_b    = (short*)W; W += (HIDD*HIDD)/2;

  k_pack<<<512, 256, 0, stream>>>(Wk_e, pk_e);
  k_pack<<<512, 256, 0, stream>>>(Wk_b, pk_b);
  k_prep_h<<<32, 256, 0, stream>>>(h, xb);
  k_mm64<<<dim3(4,2,2), 256, 0, stream>>>(
      xb+2560, 3584, Wq_e, 1024, 1024, ws_qpe, 1024,
      xb+2560, 3584, Wq_b, 1024, 1024, ws_qpb, 1024);
  k_energy<<<dim3(32,BB), 256, 0, stream>>>(enc, bwd, pk_e, pk_b,
      ws_qpe, ws_qpb, v_e, v_b, ws_ep);
  k_softmax_t<<<dim3(BB,2), 256, 0, stream>>>(ws_ep, smask, ws_atte, ws_attb);
  k_ctx<<<dim3(BB,2,8), 256, 0, stream>>>(enc, bwd, ws_atte, ws_attb, ws_ctxp);
  k_ctxred<<<512, 256, 0, stream>>>(ws_ctxp, ws_ctxe, ws_ctxb);
  k_prep_x2<<<80, 256, 0, stream>>>(tab, y, ws_ctxe, ws_ctxb, xb);
  // gates: z=0 x@W_ih^T (K=2560, 4 splits -> slots 0-3); z=1 h@W_hh^T (K=1024, 4 splits -> slots 4-7)
  k_mm64<<<dim3(16,4,2), 256, 0, stream>>>(
      xb,      3584, W_ih, 2560, 2560, ws_gp,             G4,
      xb+2560, 3584, W_hh, 1024, 1024, ws_gp + 4*BB*G4,   G4);
  k_lstm<<<256, 256, 0, stream>>>(ws_gp, b_ih, b_hh, c, out, hb);
  k_vocab2<<<250, 256, 0, stream>>>(hb, Wp, bp, out);
  k_final<<<BB, 1024, 0, stream>>>(ws_ctxe, tab, y, wc, wsv, wy, pgb, out, ws_pgen);
  k_scatter<<<128, 256, 0, stream>>>(sids, ws_atte, ws_pgen, out);
}